// Round 4
// baseline (718.738 us; speedup 1.0000x reference)
//
#include <hip/hip_runtime.h>

#define B_ 4
#define N_ 1024
#define D_ 1024
#define H_ 16
#define HD_ 64
#define E_ 12
#define T_ 4096
#define FF_ 4096

static constexpr size_t SZ_ = (size_t)T_ * D_;

typedef __attribute__((ext_vector_type(8))) short bhalf8;
typedef __attribute__((ext_vector_type(4))) float f32x4;

#define GLDS(gp, lp)                                                         \
  __builtin_amdgcn_global_load_lds(                                          \
      (const __attribute__((address_space(1))) void*)(gp),                   \
      (__attribute__((address_space(3))) void*)(lp), 16, 0, 0)

__device__ __forceinline__ float wave_sum64(float v) {
#pragma unroll
  for (int o = 32; o > 0; o >>= 1) v += __shfl_down(v, o);
  return v;
}

__device__ __forceinline__ unsigned short f2bf(float f) {
  unsigned u = __float_as_uint(f);
  u += 0x7FFFu + ((u >> 16) & 1u);
  return (unsigned short)(u >> 16);
}
__device__ __forceinline__ float b2f(unsigned short s) {
  return __uint_as_float(((unsigned)s) << 16);
}
__device__ __forceinline__ unsigned addpair_bf(unsigned x, unsigned y) {
  float lo = b2f((unsigned short)(x & 0xffff)) + b2f((unsigned short)(y & 0xffff));
  float hi = b2f((unsigned short)(x >> 16)) + b2f((unsigned short)(y >> 16));
  return (unsigned)f2bf(lo) | ((unsigned)f2bf(hi) << 16);
}

__device__ __forceinline__ float gelu_f(float x) {
  float u = 0.7978845608028654f * (x + 0.044715f * x * x * x);
  u = fminf(fmaxf(u, -15.f), 15.f);
  float e = __expf(2.f * u);
  float th = (e - 1.f) / (e + 1.f);
  return 0.5f * x * (1.f + th);
}

// swizzled LDS slot for (row, kseg): keeps glds lane-contiguity AND 2-way-max
// bank aliasing on ds_read_b128 frag reads
__device__ __forceinline__ int slot_of(int row, int q) {
  return row * 4 + (q ^ ((row >> 1) & 3));
}

// ---------------- LayerNorm: bf16 out only ----------------------------------
__global__ __launch_bounds__(256) void ln_kernel(const float* __restrict__ x,
    const float* __restrict__ g, const float* __restrict__ b,
    unsigned short* __restrict__ outb) {
  const int t = blockIdx.x, tid = threadIdx.x;
  const size_t base = (size_t)t * D_;
  const float4 v = ((const float4*)(x + base))[tid];
  float s = v.x + v.y + v.z + v.w;
  float s2 = v.x * v.x + v.y * v.y + v.z * v.z + v.w * v.w;
  s = wave_sum64(s);
  s2 = wave_sum64(s2);
  __shared__ float ls[4], ls2[4];
  const int w = tid >> 6;
  if ((tid & 63) == 0) { ls[w] = s; ls2[w] = s2; }
  __syncthreads();
  const float mean = (ls[0] + ls[1] + ls[2] + ls[3]) * (1.0f / D_);
  const float var = (ls2[0] + ls2[1] + ls2[2] + ls2[3]) * (1.0f / D_) - mean * mean;
  const float inv = rsqrtf(var + 1e-5f);
  const float4 gg = ((const float4*)g)[tid];
  const float4 bb = ((const float4*)b)[tid];
  ushort4 u4;
  u4.x = f2bf((v.x - mean) * inv * gg.x + bb.x);
  u4.y = f2bf((v.y - mean) * inv * gg.y + bb.y);
  u4.z = f2bf((v.z - mean) * inv * gg.z + bb.z);
  u4.w = f2bf((v.w - mean) * inv * gg.w + bb.w);
  ((ushort4*)(outb + base))[tid] = u4;
}

// ---- h = x + o0 + o1; y = h + b2 (fp32, pre-init for ffn2); hn bf16 --------
__global__ __launch_bounds__(256) void hln2_kernel(const float* __restrict__ x,
    const unsigned short* __restrict__ oa, const unsigned short* __restrict__ ob,
    const float* __restrict__ g, const float* __restrict__ be,
    const float* __restrict__ b2, float* __restrict__ y,
    unsigned short* __restrict__ hnb) {
  const int t = blockIdx.x, tid = threadIdx.x;
  const size_t base = (size_t)t * D_;
  const float4 xv = ((const float4*)(x + base))[tid];
  const ushort4 av = ((const ushort4*)(oa + base))[tid];
  const ushort4 bv = ((const ushort4*)(ob + base))[tid];
  float4 hv;
  hv.x = xv.x + b2f(av.x) + b2f(bv.x);
  hv.y = xv.y + b2f(av.y) + b2f(bv.y);
  hv.z = xv.z + b2f(av.z) + b2f(bv.z);
  hv.w = xv.w + b2f(av.w) + b2f(bv.w);
  const float4 b2v = ((const float4*)b2)[tid];
  float4 yv;
  yv.x = hv.x + b2v.x; yv.y = hv.y + b2v.y;
  yv.z = hv.z + b2v.z; yv.w = hv.w + b2v.w;
  ((float4*)(y + base))[tid] = yv;
  float s = hv.x + hv.y + hv.z + hv.w;
  float s2 = hv.x * hv.x + hv.y * hv.y + hv.z * hv.z + hv.w * hv.w;
  s = wave_sum64(s);
  s2 = wave_sum64(s2);
  __shared__ float ls[4], ls2[4];
  const int w = tid >> 6;
  if ((tid & 63) == 0) { ls[w] = s; ls2[w] = s2; }
  __syncthreads();
  const float mean = (ls[0] + ls[1] + ls[2] + ls[3]) * (1.0f / D_);
  const float var = (ls2[0] + ls2[1] + ls2[2] + ls2[3]) * (1.0f / D_) - mean * mean;
  const float inv = rsqrtf(var + 1e-5f);
  const float4 gg = ((const float4*)g)[tid];
  const float4 bb = ((const float4*)be)[tid];
  ushort4 o4;
  o4.x = f2bf((hv.x - mean) * inv * gg.x + bb.x);
  o4.y = f2bf((hv.y - mean) * inv * gg.y + bb.y);
  o4.z = f2bf((hv.z - mean) * inv * gg.z + bb.z);
  o4.w = f2bf((hv.w - mean) * inv * gg.w + bb.w);
  ((ushort4*)(hnb + base))[tid] = o4;
}

// ------- Router fused with LN1 (fp32 path, deterministic selection) ---------
__global__ __launch_bounds__(256) void router_ln(const float* __restrict__ x,
    const float* __restrict__ g, const float* __restrict__ b,
    const float* __restrict__ Wr, float* __restrict__ probs,
    int* __restrict__ topi, float2* __restrict__ topw) {
  const int t = blockIdx.x, tid = threadIdx.x;
  const float4 xv = ((const float4*)(x + (size_t)t * D_))[tid];
  float s = xv.x + xv.y + xv.z + xv.w;
  float s2 = xv.x * xv.x + xv.y * xv.y + xv.z * xv.z + xv.w * xv.w;
  s = wave_sum64(s);
  s2 = wave_sum64(s2);
  __shared__ float ls[4], ls2[4];
  const int w = tid >> 6;
  if ((tid & 63) == 0) { ls[w] = s; ls2[w] = s2; }
  __syncthreads();
  const float mean = (ls[0] + ls[1] + ls[2] + ls[3]) * (1.0f / D_);
  const float var = (ls2[0] + ls2[1] + ls2[2] + ls2[3]) * (1.0f / D_) - mean * mean;
  const float inv = rsqrtf(var + 1e-5f);
  const float4 gg = ((const float4*)g)[tid];
  const float4 bb = ((const float4*)b)[tid];
  float4 xn4;
  xn4.x = (xv.x - mean) * inv * gg.x + bb.x;
  xn4.y = (xv.y - mean) * inv * gg.y + bb.y;
  xn4.z = (xv.z - mean) * inv * gg.z + bb.z;
  xn4.w = (xv.w - mean) * inv * gg.w + bb.w;
  float acc[E_];
#pragma unroll
  for (int e = 0; e < E_; ++e) {
    const float4 wv = ((const float4*)(Wr + (size_t)e * D_))[tid];
    acc[e] = xn4.x * wv.x + xn4.y * wv.y + xn4.z * wv.z + xn4.w * wv.w;
  }
#pragma unroll
  for (int e = 0; e < E_; ++e) acc[e] = wave_sum64(acc[e]);
  __shared__ float red[4][E_];
  if ((tid & 63) == 0) {
#pragma unroll
    for (int e = 0; e < E_; ++e) red[w][e] = acc[e];
  }
  __syncthreads();
  if (tid == 0) {
    float lg[E_];
    float mx = -1e30f;
#pragma unroll
    for (int e = 0; e < E_; ++e) {
      lg[e] = red[0][e] + red[1][e] + red[2][e] + red[3][e];
      mx = fmaxf(mx, lg[e]);
    }
    float p[E_];
    float sum = 0.f;
#pragma unroll
    for (int e = 0; e < E_; ++e) { p[e] = __expf(lg[e] - mx); sum += p[e]; }
    const float invs = 1.f / sum;
#pragma unroll
    for (int e = 0; e < E_; ++e) {
      p[e] *= invs;
      probs[t * E_ + e] = p[e];
    }
    int i0 = 0;
#pragma unroll
    for (int e = 1; e < E_; ++e) if (p[e] > p[i0]) i0 = e;
    int i1 = (i0 == 0) ? 1 : 0;
#pragma unroll
    for (int e = 0; e < E_; ++e) if (e != i0 && p[e] > p[i1]) i1 = e;
    const float rs = 1.f / (p[i0] + p[i1] + 1e-6f);
    topi[t] = i0 | (i1 << 8);
    topw[t] = make_float2(p[i0] * rs, p[i1] * rs);
  }
}

__global__ __launch_bounds__(256) void psum_kernel(const float* __restrict__ probs,
                                                   float* __restrict__ psum) {
  const int tid = threadIdx.x;
  float local[E_] = {};
  for (int t = tid; t < T_; t += 256) {
#pragma unroll
    for (int e = 0; e < E_; ++e) local[e] += probs[t * E_ + e];
  }
#pragma unroll
  for (int e = 0; e < E_; ++e) local[e] = wave_sum64(local[e]);
  __shared__ float red[4][E_];
  const int w = tid >> 6;
  if ((tid & 63) == 0) {
#pragma unroll
    for (int e = 0; e < E_; ++e) red[w][e] = local[e];
  }
  __syncthreads();
  if (tid < E_)
    psum[tid] = red[0][tid] + red[1][tid] + red[2][tid] + red[3][tid];
}

__global__ __launch_bounds__(256) void build_lists(const int* __restrict__ topi,
    const float2* __restrict__ topw, int* __restrict__ ecnt,
    int* __restrict__ etok, float* __restrict__ ewt) {
  const int e = blockIdx.x;
  const int tid = threadIdx.x;
  const int wid = tid >> 6, lane = tid & 63;
  __shared__ int wbase[4];
  __shared__ int base;
  if (tid == 0) base = 0;
  __syncthreads();
  for (int c = 0; c < T_; c += 256) {
    const int t = c + tid;
    const int pk = topi[t];
    const int i0 = pk & 0xFF, i1 = (pk >> 8) & 0xFF;
    const float2 w2 = topw[t];
    const int sel = (i0 == e) ? 0 : ((i1 == e) ? 1 : -1);
    const unsigned long long mask = __ballot(sel >= 0);
    const int prefix = __popcll(mask & ((1ULL << lane) - 1ULL));
    if (lane == 0) wbase[wid] = __popcll(mask);
    __syncthreads();
    if (tid == 0) {
      int s = base;
#pragma unroll
      for (int ww = 0; ww < 4; ++ww) { int cc = wbase[ww]; wbase[ww] = s; s += cc; }
      base = s;
    }
    __syncthreads();
    if (sel >= 0) {
      const int pos = wbase[wid] + prefix;
      etok[e * T_ + pos] = t | (sel << 16);
      ewt[e * T_ + pos] = sel ? w2.y : w2.x;
    }
    __syncthreads();
  }
  if (tid == 0) ecnt[e] = base;
}

// -------- fp32 -> bf16 weight conversion (float4 per thread) ----------------
__global__ __launch_bounds__(256) void cvtw_kernel(const float* __restrict__ src,
    unsigned short* __restrict__ dst) {
  const size_t i = (size_t)blockIdx.x * 256 + threadIdx.x;
  const float4 v = ((const float4*)src)[i];
  ushort4 o;
  o.x = f2bf(v.x); o.y = f2bf(v.y); o.z = f2bf(v.z); o.w = f2bf(v.w);
  ((ushort4*)dst)[i] = o;
}

// ------- MoE gathered MFMA GEMM, BM=64 for occupancy (ragged expert M) ------
// out[kk*kkStride + tok*D + n] = bf16( w * (A[tok] @ We.T) )
__global__ __launch_bounds__(256) void moe_mfma(const unsigned short* __restrict__ Ab,
    const unsigned short* __restrict__ Wb, unsigned short* __restrict__ out,
    size_t kkStride, const int* __restrict__ ecnt, const int* __restrict__ etok,
    const float* __restrict__ ewt) {
  const int e = blockIdx.z;
  const int Me = ecnt[e];
  const int m0 = blockIdx.y * 64;
  if (m0 >= Me) return;
  const int n0 = blockIdx.x * 128;
  const unsigned short* W = Wb + (size_t)e * D_ * D_;
  __shared__ __align__(16) unsigned short As[64 * 32];
  __shared__ __align__(16) unsigned short Bs[128 * 32];
  __shared__ int stok[64];
  __shared__ float swt[64];
  const int tid = threadIdx.x;
  if (tid < 64) {
    const int s = m0 + tid;
    if (s < Me) { stok[tid] = etok[e * T_ + s]; swt[tid] = ewt[e * T_ + s]; }
    else        { stok[tid] = 0;                swt[tid] = 0.f; }
  }
  __syncthreads();
  // A: 64 rows x 4 segs = 1 GLDS/thread; B: 128 rows x 4 segs = 2 GLDS/thread
  const int ra = tid >> 2, qa = (tid & 3) ^ ((ra >> 1) & 3);
  const int s0 = tid, s1 = tid + 256;
  const int rb0 = s0 >> 2, qb0 = (s0 & 3) ^ ((rb0 >> 1) & 3);
  const int rb1 = s1 >> 2, qb1 = (s1 & 3) ^ ((rb1 >> 1) & 3);
  const unsigned short* aP  = Ab + (size_t)(stok[ra] & 0xFFFF) * D_ + qa * 8;
  const unsigned short* bP0 = W + (size_t)(n0 + rb0) * D_ + qb0 * 8;
  const unsigned short* bP1 = W + (size_t)(n0 + rb1) * D_ + qb1 * 8;
  char* AsC = (char*)As;
  char* BsC = (char*)Bs;
  const int wave = tid >> 6, lane = tid & 63;
  const int wn0 = wave * 32;
  const int lr = lane & 15, lq = lane >> 4;
  int aoff[4], boff[2];
#pragma unroll
  for (int t = 0; t < 4; ++t) aoff[t] = slot_of(t * 16 + lr, lq) * 16;
#pragma unroll
  for (int t = 0; t < 2; ++t) boff[t] = slot_of(wn0 + t * 16 + lr, lq) * 16;
  f32x4 acc[4][2];
#pragma unroll
  for (int i = 0; i < 4; ++i)
#pragma unroll
    for (int j = 0; j < 2; ++j) acc[i][j] = (f32x4){0.f, 0.f, 0.f, 0.f};
  for (int kt = 0; kt < D_; kt += 32) {
    __syncthreads();
    GLDS(aP + kt, AsC + tid * 16);
    GLDS(bP0 + kt, BsC + s0 * 16);
    GLDS(bP1 + kt, BsC + s1 * 16);
    __syncthreads();
    bhalf8 af[4], bfr[2];
#pragma unroll
    for (int t = 0; t < 4; ++t) af[t] = *(const bhalf8*)(AsC + aoff[t]);
#pragma unroll
    for (int t = 0; t < 2; ++t) bfr[t] = *(const bhalf8*)(BsC + boff[t]);
#pragma unroll
    for (int i = 0; i < 4; ++i)
#pragma unroll
      for (int j = 0; j < 2; ++j)
        acc[i][j] = __builtin_amdgcn_mfma_f32_16x16x32_bf16(af[i], bfr[j], acc[i][j], 0, 0, 0);
  }
#pragma unroll
  for (int mt = 0; mt < 4; ++mt)
#pragma unroll
    for (int nt = 0; nt < 2; ++nt) {
      const f32x4 c = acc[mt][nt];
      const int col = n0 + wn0 + nt * 16 + lr;
#pragma unroll
      for (int r = 0; r < 4; ++r) {
        const int row = mt * 16 + lq * 4 + r;
        if (m0 + row < Me) {
          const int pk = stok[row];
          out[(size_t)(pk >> 16) * kkStride + (size_t)(pk & 0xFFFF) * D_ + col] =
              f2bf(c[r] * swt[row]);
        }
      }
    }
}

// ------- FFN1 MFMA: midb = bf16(gelu(hnb @ W1b.T + b1)) ---------------------
__global__ __launch_bounds__(256) void ffn1_mfma(const unsigned short* __restrict__ Ab,
    const unsigned short* __restrict__ Bb, const float* __restrict__ bias,
    unsigned short* __restrict__ mid) {
  const int m0 = blockIdx.y * 128, n0 = blockIdx.x * 128;
  __shared__ __align__(16) unsigned short As[128 * 32];
  __shared__ __align__(16) unsigned short Bs[128 * 32];
  const int tid = threadIdx.x;
  const int s0 = tid, s1 = tid + 256;
  const int r0 = s0 >> 2, q0 = (s0 & 3) ^ ((r0 >> 1) & 3);
  const int r1 = s1 >> 2, q1 = (s1 & 3) ^ ((r1 >> 1) & 3);
  const unsigned short* aP0 = Ab + (size_t)(m0 + r0) * D_ + q0 * 8;
  const unsigned short* aP1 = Ab + (size_t)(m0 + r1) * D_ + q1 * 8;
  const unsigned short* bP0 = Bb + (size_t)(n0 + r0) * D_ + q0 * 8;
  const unsigned short* bP1 = Bb + (size_t)(n0 + r1) * D_ + q1 * 8;
  char* AsC = (char*)As;
  char* BsC = (char*)Bs;
  const int wave = tid >> 6, lane = tid & 63;
  const int wm0 = (wave >> 1) * 64, wn0 = (wave & 1) * 64;
  const int lr = lane & 15, lq = lane >> 4;
  int aoff[4], boff[4];
#pragma unroll
  for (int t = 0; t < 4; ++t) {
    aoff[t] = slot_of(wm0 + t * 16 + lr, lq) * 16;
    boff[t] = slot_of(wn0 + t * 16 + lr, lq) * 16;
  }
  f32x4 acc[4][4];
#pragma unroll
  for (int i = 0; i < 4; ++i)
#pragma unroll
    for (int j = 0; j < 4; ++j) acc[i][j] = (f32x4){0.f, 0.f, 0.f, 0.f};
  for (int kt = 0; kt < D_; kt += 32) {
    __syncthreads();
    GLDS(aP0 + kt, AsC + s0 * 16);
    GLDS(aP1 + kt, AsC + s1 * 16);
    GLDS(bP0 + kt, BsC + s0 * 16);
    GLDS(bP1 + kt, BsC + s1 * 16);
    __syncthreads();
    bhalf8 af[4], bfr[4];
#pragma unroll
    for (int t = 0; t < 4; ++t) af[t] = *(const bhalf8*)(AsC + aoff[t]);
#pragma unroll
    for (int t = 0; t < 4; ++t) bfr[t] = *(const bhalf8*)(BsC + boff[t]);
#pragma unroll
    for (int i = 0; i < 4; ++i)
#pragma unroll
      for (int j = 0; j < 4; ++j)
        acc[i][j] = __builtin_amdgcn_mfma_f32_16x16x32_bf16(af[i], bfr[j], acc[i][j], 0, 0, 0);
  }
  float bcol[4];
#pragma unroll
  for (int nt = 0; nt < 4; ++nt) bcol[nt] = bias[n0 + wn0 + nt * 16 + lr];
#pragma unroll
  for (int mt = 0; mt < 4; ++mt)
#pragma unroll
    for (int nt = 0; nt < 4; ++nt) {
      const f32x4 c = acc[mt][nt];
      const int col = n0 + wn0 + nt * 16 + lr;
#pragma unroll
      for (int r = 0; r < 4; ++r) {
        const int row = m0 + wm0 + mt * 16 + lq * 4 + r;
        mid[(size_t)row * FF_ + col] = f2bf(gelu_f(c[r] + bcol[nt]));
      }
    }
}

// ------- FFN2 split-K=4 MFMA: z0 accumulates into y; z1..3 -> fp32 partials -
__global__ __launch_bounds__(256) void ffn2_split4(const unsigned short* __restrict__ Ab,
    const unsigned short* __restrict__ Bb, float* __restrict__ y,
    float* __restrict__ p1, float* __restrict__ p2, float* __restrict__ p3) {
  const int m0 = blockIdx.y * 128, n0 = blockIdx.x * 128;
  const int z = blockIdx.z;
  const int k0 = z * (FF_ / 4);
  float* const dst = (z == 0) ? y : ((z == 1) ? p1 : ((z == 2) ? p2 : p3));
  const bool rmw = (z == 0);
  __shared__ __align__(16) unsigned short As[128 * 32];
  __shared__ __align__(16) unsigned short Bs[128 * 32];
  const int tid = threadIdx.x;
  const int s0 = tid, s1 = tid + 256;
  const int r0 = s0 >> 2, q0 = (s0 & 3) ^ ((r0 >> 1) & 3);
  const int r1 = s1 >> 2, q1 = (s1 & 3) ^ ((r1 >> 1) & 3);
  const unsigned short* aP0 = Ab + (size_t)(m0 + r0) * FF_ + q0 * 8 + k0;
  const unsigned short* aP1 = Ab + (size_t)(m0 + r1) * FF_ + q1 * 8 + k0;
  const unsigned short* bP0 = Bb + (size_t)(n0 + r0) * FF_ + q0 * 8 + k0;
  const unsigned short* bP1 = Bb + (size_t)(n0 + r1) * FF_ + q1 * 8 + k0;
  char* AsC = (char*)As;
  char* BsC = (char*)Bs;
  const int wave = tid >> 6, lane = tid & 63;
  const int wm0 = (wave >> 1) * 64, wn0 = (wave & 1) * 64;
  const int lr = lane & 15, lq = lane >> 4;
  int aoff[4], boff[4];
#pragma unroll
  for (int t = 0; t < 4; ++t) {
    aoff[t] = slot_of(wm0 + t * 16 + lr, lq) * 16;
    boff[t] = slot_of(wn0 + t * 16 + lr, lq) * 16;
  }
  f32x4 acc[4][4];
#pragma unroll
  for (int i = 0; i < 4; ++i)
#pragma unroll
    for (int j = 0; j < 4; ++j) acc[i][j] = (f32x4){0.f, 0.f, 0.f, 0.f};
  for (int kt = 0; kt < FF_ / 4; kt += 32) {
    __syncthreads();
    GLDS(aP0 + kt, AsC + s0 * 16);
    GLDS(aP1 + kt, AsC + s1 * 16);
    GLDS(bP0 + kt, BsC + s0 * 16);
    GLDS(bP1 + kt, BsC + s1 * 16);
    __syncthreads();
    bhalf8 af[4], bfr[4];
#pragma unroll
    for (int t = 0; t < 4; ++t) af[t] = *(const bhalf8*)(AsC + aoff[t]);
#pragma unroll
    for (int t = 0; t < 4; ++t) bfr[t] = *(const bhalf8*)(BsC + boff[t]);
#pragma unroll
    for (int i = 0; i < 4; ++i)
#pragma unroll
      for (int j = 0; j < 4; ++j)
        acc[i][j] = __builtin_amdgcn_mfma_f32_16x16x32_bf16(af[i], bfr[j], acc[i][j], 0, 0, 0);
  }
#pragma unroll
  for (int mt = 0; mt < 4; ++mt)
#pragma unroll
    for (int nt = 0; nt < 4; ++nt) {
      const f32x4 c = acc[mt][nt];
      const int col = n0 + wn0 + nt * 16 + lr;
#pragma unroll
      for (int r = 0; r < 4; ++r) {
        const int row = m0 + wm0 + mt * 16 + lq * 4 + r;
        const size_t idx = (size_t)row * D_ + col;
        if (rmw) dst[idx] += c[r];
        else     dst[idx] = c[r];
      }
    }
}

// ---------------- y += p1 + p2 + p3 (float4 per thread) ---------------------
__global__ __launch_bounds__(256) void addf_kernel(float* __restrict__ y,
    const float* __restrict__ p1, const float* __restrict__ p2,
    const float* __restrict__ p3) {
  const size_t i = (size_t)blockIdx.x * 256 + threadIdx.x;
  const float4 a = ((const float4*)y)[i];
  const float4 u = ((const float4*)p1)[i];
  const float4 v = ((const float4*)p2)[i];
  const float4 w = ((const float4*)p3)[i];
  float4 o;
  o.x = a.x + u.x + v.x + w.x;
  o.y = a.y + u.y + v.y + w.y;
  o.z = a.z + u.z + v.z + w.z;
  o.w = a.w + u.w + v.w + w.w;
  ((float4*)y)[i] = o;
}

// ------- bf16 in-place slot0 += slot1 for 3 regions spaced 2*SZ -------------
__global__ __launch_bounds__(256) void add2b3_kernel(unsigned short* __restrict__ base) {
  const int reg = blockIdx.x >> 11;             // 2048 blocks per region
  const int ib = blockIdx.x & 2047;
  unsigned short* a = base + (size_t)reg * 2 * SZ_;
  const unsigned short* b = a + SZ_;
  const size_t i = (size_t)ib * 256 + threadIdx.x;
  uint4 av = ((uint4*)a)[i];
  const uint4 bv = ((const uint4*)b)[i];
  av.x = addpair_bf(av.x, bv.x);
  av.y = addpair_bf(av.y, bv.y);
  av.z = addpair_bf(av.z, bv.z);
  av.w = addpair_bf(av.w, bv.w);
  ((uint4*)a)[i] = av;
}

// ---------------- Flash attention (MFMA bf16, fp32 softmax) -----------------
__global__ __launch_bounds__(256) void attn_kernel(const unsigned short* __restrict__ q,
    const unsigned short* __restrict__ k, const unsigned short* __restrict__ v,
    unsigned short* __restrict__ out) {
  const int bh = blockIdx.x;
  const int b = bh >> 4, h = bh & 15;
  const int q0 = blockIdx.y * 64;
  const int tid = threadIdx.x;
  const int wave = tid >> 6, lane = tid & 63;
  const int lc = lane & 15, lg = lane >> 4;

  __shared__ __align__(16) unsigned short Ks[64 * 64];   // [kv][d] swizzled
  __shared__ __align__(16) unsigned short Vt[64 * 64];   // [d][kv] swizzled
  __shared__ __align__(16) unsigned short Pl[4][16 * 64]; // per-wave [q][kv] swizzled
  char* const KsC = (char*)Ks;
  char* const VtC = (char*)Vt;
  char* const PlC = (char*)&Pl[wave][0];

  bhalf8 qf0, qf1;
  {
    const unsigned short* qp =
        q + ((size_t)(b * N_ + q0 + wave * 16 + lc)) * D_ + h * HD_ + lg * 8;
    qf0 = *(const bhalf8*)qp;
    qf1 = *(const bhalf8*)(qp + 32);
  }

  int off[4][2];
#pragma unroll
  for (int t = 0; t < 4; ++t)
#pragma unroll
    for (int ch = 0; ch < 2; ++ch)
      off[t][ch] = (t * 16 + lc) * 128 + (((ch * 4 + lg) ^ (lc & 7)) << 4);

  const int krow = tid >> 2, ks0 = tid & 3;
  const unsigned short* const kgp =
      k + ((size_t)(b * N_ + krow)) * D_ + h * HD_ + ks0 * 8;
  const int kwo0 = krow * 128 + ((ks0 ^ (krow & 7)) << 4);
  const int kwo1 = krow * 128 + (((ks0 ^ 4) ^ (krow & 7)) << 4);
  const int vkv = (tid & 31) * 2, vd0 = (tid >> 5) * 8;
  const unsigned short* const vgp =
      v + ((size_t)(b * N_ + vkv)) * D_ + h * HD_ + vd0;
  int vwo[8];
#pragma unroll
  for (int c = 0; c < 8; ++c) {
    const int d = vd0 + c;
    vwo[c] = d * 128 + ((((vkv >> 3) ^ (d & 7)) << 4)) + (vkv & 7) * 2;
  }

  float m_i[4], l_i[4];
  f32x4 o_acc[4];
#pragma unroll
  for (int r = 0; r < 4; ++r) { m_i[r] = -3.0e38f; l_i[r] = 0.f; }
#pragma unroll
  for (int t = 0; t < 4; ++t) o_acc[t] = (f32x4){0.f, 0.f, 0.f, 0.f};

  uint4 ka = *(const uint4*)(kgp);
  uint4 kb = *(const uint4*)(kgp + 32);
  uint4 va = *(const uint4*)(vgp);
  uint4 vb = *(const uint4*)(vgp + D_);

  for (int kt = 0; kt < 16; ++kt) {
    __syncthreads();
    *(uint4*)(KsC + kwo0) = ka;
    *(uint4*)(KsC + kwo1) = kb;
    {
      const unsigned av4[4] = {va.x, va.y, va.z, va.w};
      const unsigned bv4[4] = {vb.x, vb.y, vb.z, vb.w};
#pragma unroll
      for (int c = 0; c < 4; ++c) {
        const unsigned w0 = (av4[c] & 0xffffu) | (bv4[c] << 16);
        const unsigned w1 = (av4[c] >> 16) | (bv4[c] & 0xffff0000u);
        *(unsigned*)(VtC + vwo[2 * c]) = w0;
        *(unsigned*)(VtC + vwo[2 * c + 1]) = w1;
      }
    }
    __syncthreads();
    if (kt < 15) {
      const size_t go = (size_t)(kt + 1) * 64 * D_;
      ka = *(const uint4*)(kgp + go);
      kb = *(const uint4*)(kgp + go + 32);
      va = *(const uint4*)(vgp + go);
      vb = *(const uint4*)(vgp + go + D_);
    }
    f32x4 s4[4];
#pragma unroll
    for (int t = 0; t < 4; ++t) {
      f32x4 acc = (f32x4){0.f, 0.f, 0.f, 0.f};
      acc = __builtin_amdgcn_mfma_f32_16x16x32_bf16(
          qf0, *(const bhalf8*)(KsC + off[t][0]), acc, 0, 0, 0);
      acc = __builtin_amdgcn_mfma_f32_16x16x32_bf16(
          qf1, *(const bhalf8*)(KsC + off[t][1]), acc, 0, 0, 0);
      s4[t] = acc;
    }
    float alpha[4];
#pragma unroll
    for (int r = 0; r < 4; ++r) {
      const float e0 = s4[0][r] * 0.125f, e1 = s4[1][r] * 0.125f;
      const float e2 = s4[2][r] * 0.125f, e3 = s4[3][r] * 0.125f;
      float mt = fmaxf(fmaxf(e0, e1), fmaxf(e2, e3));
#pragma unroll
      for (int o = 8; o > 0; o >>= 1) mt = fmaxf(mt, __shfl_xor(mt, o));
      const float mn = fmaxf(m_i[r], mt);
      alpha[r] = __expf(m_i[r] - mn);
      m_i[r] = mn;
      const float p0 = __expf(e0 - mn), p1 = __expf(e1 - mn);
      const float p2 = __expf(e2 - mn), p3 = __expf(e3 - mn);
      float rs = p0 + p1 + p2 + p3;
#pragma unroll
      for (int o = 8; o > 0; o >>= 1) rs += __shfl_xor(rs, o);
      l_i[r] = l_i[r] * alpha[r] + rs;
      const int qrow = 4 * lg + r;
      const int rb = qrow * 128 + (lc & 7) * 2;
      const int sw = qrow & 7;
      *(unsigned short*)(PlC + rb + (((0 + (lc >> 3)) ^ sw) << 4)) = f2bf(p0);
      *(unsigned short*)(PlC + rb + (((2 + (lc >> 3)) ^ sw) << 4)) = f2bf(p1);
      *(unsigned short*)(PlC + rb + (((4 + (lc >> 3)) ^ sw) << 4)) = f2bf(p2);
      *(unsigned short*)(PlC + rb + (((6 + (lc >> 3)) ^ sw) << 4)) = f2bf(p3);
    }
#pragma unroll
    for (int t = 0; t < 4; ++t) {
      f32x4 o = o_acc[t];
      o[0] *= alpha[0]; o[1] *= alpha[1]; o[2] *= alpha[2]; o[3] *= alpha[3];
      o_acc[t] = o;
    }
    const bhalf8 pf0 = *(const bhalf8*)(PlC + off[0][0]);
    const bhalf8 pf1 = *(const bhalf8*)(PlC + off[0][1]);
#pragma unroll
    for (int t = 0; t < 4; ++t) {
      o_acc[t] = __builtin_amdgcn_mfma_f32_16x16x32_bf16(
          pf0, *(const bhalf8*)(VtC + off[t][0]), o_acc[t], 0, 0, 0);
      o_acc[t] = __builtin_amdgcn_mfma_f32_16x16x32_bf16(
          pf1, *(const bhalf8*)(VtC + off[t][1]), o_acc[t], 0, 0, 0);
    }
  }
  const size_t obase = ((size_t)(b * N_ + q0 + wave * 16)) * D_ + h * HD_;
#pragma unroll
  for (int r = 0; r < 4; ++r) {
    const float inv = 1.f / l_i[r];
    const size_t rbase = obase + (size_t)(4 * lg + r) * D_;
#pragma unroll
    for (int t = 0; t < 4; ++t)
      out[rbase + t * 16 + lc] = f2bf(o_acc[t][r] * inv);
  }
}

// ---------------- load-balance scalar ---------------------------------------
__global__ void lb_kernel(const int* __restrict__ ecnt,
                          const float* __restrict__ psum, float* __restrict__ out) {
  if (threadIdx.x == 0 && blockIdx.x == 0) {
    float tot = 0.f;
    for (int e = 0; e < E_; ++e) tot += (float)ecnt[e];
    float s = 0.f;
    for (int e = 0; e < E_; ++e) s += (float)ecnt[e] / (tot + 1e-6f) * psum[e];
    out[0] = s * (float)E_;
  }
}

extern "C" void kernel_launch(void* const* d_in, const int* in_sizes, int n_in,
                              void* d_out, int out_size, void* d_ws, size_t ws_size,
                              hipStream_t stream) {
  (void)in_sizes; (void)n_in; (void)out_size; (void)ws_size;
  const float* x  = (const float*)d_in[0];
  const float* Wr = (const float*)d_in[1];
  const float* Wq = (const float*)d_in[2];
  const float* Wk = (const float*)d_in[3];
  const float* Wv = (const float*)d_in[4];
  const float* Wo = (const float*)d_in[5];
  const float* W1 = (const float*)d_in[6];
  const float* b1 = (const float*)d_in[7];
  const float* W2 = (const float*)d_in[8];
  const float* b2 = (const float*)d_in[9];
  const float* g1 = (const float*)d_in[10];
  const float* be1 = (const float*)d_in[11];
  const float* g2 = (const float*)d_in[12];
  const float* be2 = (const float*)d_in[13];
  float* y = (float*)d_out;

  // ---- workspace layout (same 96.6 MB high-water as previous) -------------
  char* p = (char*)d_ws;
  unsigned short* Rb = (unsigned short*)p;   p += (size_t)E_ * D_ * D_ * 2;  // 24 MB bf16 weight scratch
  unsigned short* xnb = (unsigned short*)p;  p += SZ_ * 2;       // 8 MB bf16 LN1
  unsigned short* q2b = (unsigned short*)p;  p += 2 * SZ_ * 2;   // 16 MB [2][T][D]
  unsigned short* k2b = (unsigned short*)p;  p += 2 * SZ_ * 2;   // 16 MB
  unsigned short* v2b = (unsigned short*)p;  p += 2 * SZ_ * 2;   // 16 MB
  unsigned short* W1b = (unsigned short*)p;  p += (size_t)FF_ * D_ * 2;  // 8 MB
  unsigned short* W2b = (unsigned short*)p;  p += (size_t)FF_ * D_ * 2;  // 8 MB
  float* psum = (float*)p;               p += E_ * 4;
  int* ecnt = (int*)p;                   p += E_ * 4;
  int* etok = (int*)p;                   p += (size_t)E_ * T_ * 4;
  float* ewt = (float*)p;                p += (size_t)E_ * T_ * 4;
  float* probs = (float*)p;              p += (size_t)T_ * E_ * 4;
  int* topi = (int*)p;                   p += T_ * 4;
  float2* topw = (float2*)p;
  // overlays (regions dead at time of reuse):
  unsigned short* attb = v2b + SZ_;        // attn out (v slot1 dead after add2b3)
  unsigned short* o2b  = q2b;              // o-proj 2 slots (q dead post-attn)
  unsigned short* hnb  = v2b;              // hn bf16 (v slot0 dead post-attn)
  float* part1         = (float*)k2b;      // ffn2 partial z=1 (k dead post-attn)
  float* part2         = (float*)v2b;      // ffn2 partial z=2 (v dead post-ffn1)
  float* part3         = (float*)q2b;      // ffn2 partial z=3 (q dead post-hln2)
  unsigned short* midb = (unsigned short*)d_ws;  // 32 MB over Rb+xnb (dead by ffn1)

  // 1. LN1 (bf16 only; router recomputes LN in fp32 itself)
  ln_kernel<<<T_, 256, 0, stream>>>(x, g1, be1, xnb);
  // 2. FFN weight conversion
  cvtw_kernel<<<(FF_ * D_) / 1024, 256, 0, stream>>>(W1, W1b);
  cvtw_kernel<<<(FF_ * D_) / 1024, 256, 0, stream>>>(W2, W2b);
  // 3. Router (fused LN, fp32, deterministic)
  router_ln<<<T_, 256, 0, stream>>>(x, g1, be1, Wr, probs, topi, topw);
  psum_kernel<<<1, 256, 0, stream>>>(probs, psum);
  build_lists<<<E_, 256, 0, stream>>>(topi, topw, ecnt, etok, ewt);
  // 4. MoE projections q,k,v: convert expert weights to bf16 (serial reuse of Rb)
  dim3 gmoe(D_ / 128, T_ / 64, E_);
  const int gw = (E_ * D_ * D_) / 1024;
  cvtw_kernel<<<gw, 256, 0, stream>>>(Wq, Rb);
  moe_mfma<<<gmoe, 256, 0, stream>>>(xnb, Rb, q2b, SZ_, ecnt, etok, ewt);
  cvtw_kernel<<<gw, 256, 0, stream>>>(Wk, Rb);
  moe_mfma<<<gmoe, 256, 0, stream>>>(xnb, Rb, k2b, SZ_, ecnt, etok, ewt);
  cvtw_kernel<<<gw, 256, 0, stream>>>(Wv, Rb);
  moe_mfma<<<gmoe, 256, 0, stream>>>(xnb, Rb, v2b, SZ_, ecnt, etok, ewt);
  cvtw_kernel<<<gw, 256, 0, stream>>>(Wo, Rb);  // Rb free again after moe#3
  // 5. Combine expert slots (bf16, one dispatch over q/k/v regions)
  add2b3_kernel<<<3 * (SZ_ / 2048), 256, 0, stream>>>(q2b);
  // 6. Attention (MFMA flash; out -> v2b slot1)
  attn_kernel<<<dim3(B_ * H_, N_ / 64), 256, 0, stream>>>(q2b, k2b, v2b, attb);
  // 7. Output projection (2 slots into o2b = q2b)
  moe_mfma<<<gmoe, 256, 0, stream>>>(attb, Rb, o2b, SZ_, ecnt, etok, ewt);
  // 8. h = x + o0 + o1 ; y = h + b2 (ffn2 pre-init) ; hn = LN2(h)
  hln2_kernel<<<T_, 256, 0, stream>>>(x, o2b, o2b + SZ_, g2, be2, b2, y, hnb);
  // 9. FFN (MFMA; ffn2 split-K=4: z0 -> y RMW, z1..3 -> partials, combine)
  ffn1_mfma<<<dim3(FF_ / 128, T_ / 128), 256, 0, stream>>>(hnb, W1b, b1, midb);
  ffn2_split4<<<dim3(D_ / 128, T_ / 128, 4), 256, 0, stream>>>(midb, W2b, y, part1, part2, part3);
  addf_kernel<<<SZ_ / 1024, 256, 0, stream>>>(y, part1, part2, part3);
  // 10. load-balance scalar
  lb_kernel<<<1, 64, 0, stream>>>(ecnt, psum, y + SZ_);
}

// Round 5
// 627.740 us; speedup vs baseline: 1.1450x; 1.1450x over previous
//
#include <hip/hip_runtime.h>

#define B_ 4
#define N_ 1024
#define D_ 1024
#define H_ 16
#define HD_ 64
#define E_ 12
#define T_ 4096
#define FF_ 4096

static constexpr size_t SZ_ = (size_t)T_ * D_;

typedef __attribute__((ext_vector_type(8))) short bhalf8;
typedef __attribute__((ext_vector_type(4))) float f32x4;

#define GLDS(gp, lp)                                                         \
  __builtin_amdgcn_global_load_lds(                                          \
      (const __attribute__((address_space(1))) void*)(gp),                   \
      (__attribute__((address_space(3))) void*)(lp), 16, 0, 0)

__device__ __forceinline__ float wave_sum64(float v) {
#pragma unroll
  for (int o = 32; o > 0; o >>= 1) v += __shfl_down(v, o);
  return v;
}

__device__ __forceinline__ unsigned short f2bf(float f) {
  unsigned u = __float_as_uint(f);
  u += 0x7FFFu + ((u >> 16) & 1u);
  return (unsigned short)(u >> 16);
}
__device__ __forceinline__ float b2f(unsigned short s) {
  return __uint_as_float(((unsigned)s) << 16);
}
__device__ __forceinline__ unsigned addpair_bf(unsigned x, unsigned y) {
  float lo = b2f((unsigned short)(x & 0xffff)) + b2f((unsigned short)(y & 0xffff));
  float hi = b2f((unsigned short)(x >> 16)) + b2f((unsigned short)(y >> 16));
  return (unsigned)f2bf(lo) | ((unsigned)f2bf(hi) << 16);
}

__device__ __forceinline__ float gelu_f(float x) {
  float u = 0.7978845608028654f * (x + 0.044715f * x * x * x);
  u = fminf(fmaxf(u, -15.f), 15.f);
  float e = __expf(2.f * u);
  float th = (e - 1.f) / (e + 1.f);
  return 0.5f * x * (1.f + th);
}

// swizzled LDS slot for (row, kseg): keeps glds lane-contiguity AND 2-way-max
// bank aliasing on ds_read_b128 frag reads
__device__ __forceinline__ int slot_of(int row, int q) {
  return row * 4 + (q ^ ((row >> 1) & 3));
}

// ---------------- LayerNorm: bf16 out only ----------------------------------
__global__ __launch_bounds__(256) void ln_kernel(const float* __restrict__ x,
    const float* __restrict__ g, const float* __restrict__ b,
    unsigned short* __restrict__ outb) {
  const int t = blockIdx.x, tid = threadIdx.x;
  const size_t base = (size_t)t * D_;
  const float4 v = ((const float4*)(x + base))[tid];
  float s = v.x + v.y + v.z + v.w;
  float s2 = v.x * v.x + v.y * v.y + v.z * v.z + v.w * v.w;
  s = wave_sum64(s);
  s2 = wave_sum64(s2);
  __shared__ float ls[4], ls2[4];
  const int w = tid >> 6;
  if ((tid & 63) == 0) { ls[w] = s; ls2[w] = s2; }
  __syncthreads();
  const float mean = (ls[0] + ls[1] + ls[2] + ls[3]) * (1.0f / D_);
  const float var = (ls2[0] + ls2[1] + ls2[2] + ls2[3]) * (1.0f / D_) - mean * mean;
  const float inv = rsqrtf(var + 1e-5f);
  const float4 gg = ((const float4*)g)[tid];
  const float4 bb = ((const float4*)b)[tid];
  ushort4 u4;
  u4.x = f2bf((v.x - mean) * inv * gg.x + bb.x);
  u4.y = f2bf((v.y - mean) * inv * gg.y + bb.y);
  u4.z = f2bf((v.z - mean) * inv * gg.z + bb.z);
  u4.w = f2bf((v.w - mean) * inv * gg.w + bb.w);
  ((ushort4*)(outb + base))[tid] = u4;
}

// ---- h = x + o0 + o1; y = h + b2 (fp32, pre-init for ffn2); hn bf16 --------
__global__ __launch_bounds__(256) void hln2_kernel(const float* __restrict__ x,
    const unsigned short* __restrict__ oa, const unsigned short* __restrict__ ob,
    const float* __restrict__ g, const float* __restrict__ be,
    const float* __restrict__ b2, float* __restrict__ y,
    unsigned short* __restrict__ hnb) {
  const int t = blockIdx.x, tid = threadIdx.x;
  const size_t base = (size_t)t * D_;
  const float4 xv = ((const float4*)(x + base))[tid];
  const ushort4 av = ((const ushort4*)(oa + base))[tid];
  const ushort4 bv = ((const ushort4*)(ob + base))[tid];
  float4 hv;
  hv.x = xv.x + b2f(av.x) + b2f(bv.x);
  hv.y = xv.y + b2f(av.y) + b2f(bv.y);
  hv.z = xv.z + b2f(av.z) + b2f(bv.z);
  hv.w = xv.w + b2f(av.w) + b2f(bv.w);
  const float4 b2v = ((const float4*)b2)[tid];
  float4 yv;
  yv.x = hv.x + b2v.x; yv.y = hv.y + b2v.y;
  yv.z = hv.z + b2v.z; yv.w = hv.w + b2v.w;
  ((float4*)(y + base))[tid] = yv;
  float s = hv.x + hv.y + hv.z + hv.w;
  float s2 = hv.x * hv.x + hv.y * hv.y + hv.z * hv.z + hv.w * hv.w;
  s = wave_sum64(s);
  s2 = wave_sum64(s2);
  __shared__ float ls[4], ls2[4];
  const int w = tid >> 6;
  if ((tid & 63) == 0) { ls[w] = s; ls2[w] = s2; }
  __syncthreads();
  const float mean = (ls[0] + ls[1] + ls[2] + ls[3]) * (1.0f / D_);
  const float var = (ls2[0] + ls2[1] + ls2[2] + ls2[3]) * (1.0f / D_) - mean * mean;
  const float inv = rsqrtf(var + 1e-5f);
  const float4 gg = ((const float4*)g)[tid];
  const float4 bb = ((const float4*)be)[tid];
  ushort4 o4;
  o4.x = f2bf((hv.x - mean) * inv * gg.x + bb.x);
  o4.y = f2bf((hv.y - mean) * inv * gg.y + bb.y);
  o4.z = f2bf((hv.z - mean) * inv * gg.z + bb.z);
  o4.w = f2bf((hv.w - mean) * inv * gg.w + bb.w);
  ((ushort4*)(hnb + base))[tid] = o4;
}

// ------- Router fused with LN1 (fp32 path, deterministic selection) ---------
__global__ __launch_bounds__(256) void router_ln(const float* __restrict__ x,
    const float* __restrict__ g, const float* __restrict__ b,
    const float* __restrict__ Wr, float* __restrict__ probs,
    int* __restrict__ topi, float2* __restrict__ topw) {
  const int t = blockIdx.x, tid = threadIdx.x;
  const float4 xv = ((const float4*)(x + (size_t)t * D_))[tid];
  float s = xv.x + xv.y + xv.z + xv.w;
  float s2 = xv.x * xv.x + xv.y * xv.y + xv.z * xv.z + xv.w * xv.w;
  s = wave_sum64(s);
  s2 = wave_sum64(s2);
  __shared__ float ls[4], ls2[4];
  const int w = tid >> 6;
  if ((tid & 63) == 0) { ls[w] = s; ls2[w] = s2; }
  __syncthreads();
  const float mean = (ls[0] + ls[1] + ls[2] + ls[3]) * (1.0f / D_);
  const float var = (ls2[0] + ls2[1] + ls2[2] + ls2[3]) * (1.0f / D_) - mean * mean;
  const float inv = rsqrtf(var + 1e-5f);
  const float4 gg = ((const float4*)g)[tid];
  const float4 bb = ((const float4*)b)[tid];
  float4 xn4;
  xn4.x = (xv.x - mean) * inv * gg.x + bb.x;
  xn4.y = (xv.y - mean) * inv * gg.y + bb.y;
  xn4.z = (xv.z - mean) * inv * gg.z + bb.z;
  xn4.w = (xv.w - mean) * inv * gg.w + bb.w;
  float acc[E_];
#pragma unroll
  for (int e = 0; e < E_; ++e) {
    const float4 wv = ((const float4*)(Wr + (size_t)e * D_))[tid];
    acc[e] = xn4.x * wv.x + xn4.y * wv.y + xn4.z * wv.z + xn4.w * wv.w;
  }
#pragma unroll
  for (int e = 0; e < E_; ++e) acc[e] = wave_sum64(acc[e]);
  __shared__ float red[4][E_];
  if ((tid & 63) == 0) {
#pragma unroll
    for (int e = 0; e < E_; ++e) red[w][e] = acc[e];
  }
  __syncthreads();
  if (tid == 0) {
    float lg[E_];
    float mx = -1e30f;
#pragma unroll
    for (int e = 0; e < E_; ++e) {
      lg[e] = red[0][e] + red[1][e] + red[2][e] + red[3][e];
      mx = fmaxf(mx, lg[e]);
    }
    float p[E_];
    float sum = 0.f;
#pragma unroll
    for (int e = 0; e < E_; ++e) { p[e] = __expf(lg[e] - mx); sum += p[e]; }
    const float invs = 1.f / sum;
#pragma unroll
    for (int e = 0; e < E_; ++e) {
      p[e] *= invs;
      probs[t * E_ + e] = p[e];
    }
    int i0 = 0;
#pragma unroll
    for (int e = 1; e < E_; ++e) if (p[e] > p[i0]) i0 = e;
    int i1 = (i0 == 0) ? 1 : 0;
#pragma unroll
    for (int e = 0; e < E_; ++e) if (e != i0 && p[e] > p[i1]) i1 = e;
    const float rs = 1.f / (p[i0] + p[i1] + 1e-6f);
    topi[t] = i0 | (i1 << 8);
    topw[t] = make_float2(p[i0] * rs, p[i1] * rs);
  }
}

__global__ __launch_bounds__(256) void psum_kernel(const float* __restrict__ probs,
                                                   float* __restrict__ psum) {
  const int tid = threadIdx.x;
  float local[E_] = {};
  for (int t = tid; t < T_; t += 256) {
#pragma unroll
    for (int e = 0; e < E_; ++e) local[e] += probs[t * E_ + e];
  }
#pragma unroll
  for (int e = 0; e < E_; ++e) local[e] = wave_sum64(local[e]);
  __shared__ float red[4][E_];
  const int w = tid >> 6;
  if ((tid & 63) == 0) {
#pragma unroll
    for (int e = 0; e < E_; ++e) red[w][e] = local[e];
  }
  __syncthreads();
  if (tid < E_)
    psum[tid] = red[0][tid] + red[1][tid] + red[2][tid] + red[3][tid];
}

__global__ __launch_bounds__(256) void build_lists(const int* __restrict__ topi,
    const float2* __restrict__ topw, int* __restrict__ ecnt,
    int* __restrict__ etok, float* __restrict__ ewt) {
  const int e = blockIdx.x;
  const int tid = threadIdx.x;
  const int wid = tid >> 6, lane = tid & 63;
  __shared__ int wbase[4];
  __shared__ int base;
  if (tid == 0) base = 0;
  __syncthreads();
  for (int c = 0; c < T_; c += 256) {
    const int t = c + tid;
    const int pk = topi[t];
    const int i0 = pk & 0xFF, i1 = (pk >> 8) & 0xFF;
    const float2 w2 = topw[t];
    const int sel = (i0 == e) ? 0 : ((i1 == e) ? 1 : -1);
    const unsigned long long mask = __ballot(sel >= 0);
    const int prefix = __popcll(mask & ((1ULL << lane) - 1ULL));
    if (lane == 0) wbase[wid] = __popcll(mask);
    __syncthreads();
    if (tid == 0) {
      int s = base;
#pragma unroll
      for (int ww = 0; ww < 4; ++ww) { int cc = wbase[ww]; wbase[ww] = s; s += cc; }
      base = s;
    }
    __syncthreads();
    if (sel >= 0) {
      const int pos = wbase[wid] + prefix;
      etok[e * T_ + pos] = t | (sel << 16);
      ewt[e * T_ + pos] = sel ? w2.y : w2.x;
    }
    __syncthreads();
  }
  if (tid == 0) ecnt[e] = base;
}

// -------- fp32 -> bf16 weight conversion (float4 per thread) ----------------
__global__ __launch_bounds__(256) void cvtw_kernel(const float* __restrict__ src,
    unsigned short* __restrict__ dst) {
  const size_t i = (size_t)blockIdx.x * 256 + threadIdx.x;
  const float4 v = ((const float4*)src)[i];
  ushort4 o;
  o.x = f2bf(v.x); o.y = f2bf(v.y); o.z = f2bf(v.z); o.w = f2bf(v.w);
  ((ushort4*)dst)[i] = o;
}

// -------- 3-source weight conversion into contiguous dst regions ------------
__global__ __launch_bounds__(256) void cvtw3_kernel(const float* __restrict__ a,
    const float* __restrict__ b, const float* __restrict__ c,
    unsigned short* __restrict__ dst) {
  const int gw = (E_ * D_ * D_) / 1024;
  const int r = blockIdx.x / gw;
  const int ib = blockIdx.x - r * gw;
  const float* src = (r == 0) ? a : ((r == 1) ? b : c);
  const size_t i = (size_t)ib * 256 + threadIdx.x;
  const float4 v = ((const float4*)src)[i];
  ushort4 o;
  o.x = f2bf(v.x); o.y = f2bf(v.y); o.z = f2bf(v.z); o.w = f2bf(v.w);
  ((ushort4*)(dst + (size_t)r * E_ * D_ * D_))[i] = o;
}

// ------- MoE gathered MFMA GEMM: A bf16 (glds gather), B bf16 (glds) --------
// blockIdx.x encodes (proj, n-block): proj = bx>>3 selects weight set / output.
// out[proj][slot][tok][n] = bf16( w * (A[tok] @ W[proj][e].T) )
__global__ __launch_bounds__(256) void moe_mfma(const unsigned short* __restrict__ Ab,
    const unsigned short* __restrict__ Wb, unsigned short* __restrict__ outb,
    const int* __restrict__ ecnt, const int* __restrict__ etok,
    const float* __restrict__ ewt) {
  const int e = blockIdx.z;
  const int Me = ecnt[e];
  const int m0 = blockIdx.y * 128;
  if (m0 >= Me) return;
  const int proj = blockIdx.x >> 3;
  const int n0 = (blockIdx.x & 7) * 128;
  const unsigned short* W = Wb + ((size_t)proj * E_ + e) * D_ * D_;
  unsigned short* out = outb + (size_t)proj * 2 * SZ_;
  __shared__ __align__(16) unsigned short As[128 * 32];
  __shared__ __align__(16) unsigned short Bs[128 * 32];
  __shared__ int stok[128];
  __shared__ float swt[128];
  const int tid = threadIdx.x;
  if (tid < 128) {
    const int s = m0 + tid;
    if (s < Me) { stok[tid] = etok[e * T_ + s]; swt[tid] = ewt[e * T_ + s]; }
    else        { stok[tid] = 0;                swt[tid] = 0.f; }
  }
  __syncthreads();
  const int s0 = tid, s1 = tid + 256;
  const int r0 = s0 >> 2, q0 = (s0 & 3) ^ ((r0 >> 1) & 3);
  const int r1 = s1 >> 2, q1 = (s1 & 3) ^ ((r1 >> 1) & 3);
  const unsigned short* aP0 = Ab + (size_t)(stok[r0] & 0xFFFF) * D_ + q0 * 8;
  const unsigned short* aP1 = Ab + (size_t)(stok[r1] & 0xFFFF) * D_ + q1 * 8;
  const unsigned short* bP0 = W + (size_t)(n0 + r0) * D_ + q0 * 8;
  const unsigned short* bP1 = W + (size_t)(n0 + r1) * D_ + q1 * 8;
  char* AsC = (char*)As;
  char* BsC = (char*)Bs;
  const int wave = tid >> 6, lane = tid & 63;
  const int wm0 = (wave >> 1) * 64, wn0 = (wave & 1) * 64;
  const int lr = lane & 15, lq = lane >> 4;
  int aoff[4], boff[4];
#pragma unroll
  for (int t = 0; t < 4; ++t) {
    aoff[t] = slot_of(wm0 + t * 16 + lr, lq) * 16;
    boff[t] = slot_of(wn0 + t * 16 + lr, lq) * 16;
  }
  f32x4 acc[4][4];
#pragma unroll
  for (int i = 0; i < 4; ++i)
#pragma unroll
    for (int j = 0; j < 4; ++j) acc[i][j] = (f32x4){0.f, 0.f, 0.f, 0.f};
  for (int kt = 0; kt < D_; kt += 32) {
    __syncthreads();
    GLDS(aP0 + kt, AsC + s0 * 16);
    GLDS(aP1 + kt, AsC + s1 * 16);
    GLDS(bP0 + kt, BsC + s0 * 16);
    GLDS(bP1 + kt, BsC + s1 * 16);
    __syncthreads();
    bhalf8 af[4], bfr[4];
#pragma unroll
    for (int t = 0; t < 4; ++t) af[t] = *(const bhalf8*)(AsC + aoff[t]);
#pragma unroll
    for (int t = 0; t < 4; ++t) bfr[t] = *(const bhalf8*)(BsC + boff[t]);
#pragma unroll
    for (int i = 0; i < 4; ++i)
#pragma unroll
      for (int j = 0; j < 4; ++j)
        acc[i][j] = __builtin_amdgcn_mfma_f32_16x16x32_bf16(af[i], bfr[j], acc[i][j], 0, 0, 0);
  }
#pragma unroll
  for (int mt = 0; mt < 4; ++mt)
#pragma unroll
    for (int nt = 0; nt < 4; ++nt) {
      const f32x4 c = acc[mt][nt];
      const int col = n0 + wn0 + nt * 16 + lr;
#pragma unroll
      for (int r = 0; r < 4; ++r) {
        const int row = wm0 + mt * 16 + lq * 4 + r;
        if (m0 + row < Me) {
          const int pk = stok[row];
          out[(size_t)(pk >> 16) * SZ_ + (size_t)(pk & 0xFFFF) * D_ + col] =
              f2bf(c[r] * swt[row]);
        }
      }
    }
}

// ------- FFN1 MFMA: midb = bf16(gelu(hnb @ W1b.T + b1)) ---------------------
__global__ __launch_bounds__(256) void ffn1_mfma(const unsigned short* __restrict__ Ab,
    const unsigned short* __restrict__ Bb, const float* __restrict__ bias,
    unsigned short* __restrict__ mid) {
  const int m0 = blockIdx.y * 128, n0 = blockIdx.x * 128;
  __shared__ __align__(16) unsigned short As[128 * 32];
  __shared__ __align__(16) unsigned short Bs[128 * 32];
  const int tid = threadIdx.x;
  const int s0 = tid, s1 = tid + 256;
  const int r0 = s0 >> 2, q0 = (s0 & 3) ^ ((r0 >> 1) & 3);
  const int r1 = s1 >> 2, q1 = (s1 & 3) ^ ((r1 >> 1) & 3);
  const unsigned short* aP0 = Ab + (size_t)(m0 + r0) * D_ + q0 * 8;
  const unsigned short* aP1 = Ab + (size_t)(m0 + r1) * D_ + q1 * 8;
  const unsigned short* bP0 = Bb + (size_t)(n0 + r0) * D_ + q0 * 8;
  const unsigned short* bP1 = Bb + (size_t)(n0 + r1) * D_ + q1 * 8;
  char* AsC = (char*)As;
  char* BsC = (char*)Bs;
  const int wave = tid >> 6, lane = tid & 63;
  const int wm0 = (wave >> 1) * 64, wn0 = (wave & 1) * 64;
  const int lr = lane & 15, lq = lane >> 4;
  int aoff[4], boff[4];
#pragma unroll
  for (int t = 0; t < 4; ++t) {
    aoff[t] = slot_of(wm0 + t * 16 + lr, lq) * 16;
    boff[t] = slot_of(wn0 + t * 16 + lr, lq) * 16;
  }
  f32x4 acc[4][4];
#pragma unroll
  for (int i = 0; i < 4; ++i)
#pragma unroll
    for (int j = 0; j < 4; ++j) acc[i][j] = (f32x4){0.f, 0.f, 0.f, 0.f};
  for (int kt = 0; kt < D_; kt += 32) {
    __syncthreads();
    GLDS(aP0 + kt, AsC + s0 * 16);
    GLDS(aP1 + kt, AsC + s1 * 16);
    GLDS(bP0 + kt, BsC + s0 * 16);
    GLDS(bP1 + kt, BsC + s1 * 16);
    __syncthreads();
    bhalf8 af[4], bfr[4];
#pragma unroll
    for (int t = 0; t < 4; ++t) af[t] = *(const bhalf8*)(AsC + aoff[t]);
#pragma unroll
    for (int t = 0; t < 4; ++t) bfr[t] = *(const bhalf8*)(BsC + boff[t]);
#pragma unroll
    for (int i = 0; i < 4; ++i)
#pragma unroll
      for (int j = 0; j < 4; ++j)
        acc[i][j] = __builtin_amdgcn_mfma_f32_16x16x32_bf16(af[i], bfr[j], acc[i][j], 0, 0, 0);
  }
  float bcol[4];
#pragma unroll
  for (int nt = 0; nt < 4; ++nt) bcol[nt] = bias[n0 + wn0 + nt * 16 + lr];
#pragma unroll
  for (int mt = 0; mt < 4; ++mt)
#pragma unroll
    for (int nt = 0; nt < 4; ++nt) {
      const f32x4 c = acc[mt][nt];
      const int col = n0 + wn0 + nt * 16 + lr;
#pragma unroll
      for (int r = 0; r < 4; ++r) {
        const int row = m0 + wm0 + mt * 16 + lq * 4 + r;
        mid[(size_t)row * FF_ + col] = f2bf(gelu_f(c[r] + bcol[nt]));
      }
    }
}

// ------- FFN2 split-K=2 MFMA: part[z] = midb[:, zK:(z+1)K] @ W2b[...].T -----
__global__ __launch_bounds__(256) void ffn2_split(const unsigned short* __restrict__ Ab,
    const unsigned short* __restrict__ Bb, float* __restrict__ part0,
    float* __restrict__ part1) {
  const int m0 = blockIdx.y * 128, n0 = blockIdx.x * 128;
  const int k0 = blockIdx.z * (FF_ / 2);
  float* const part = blockIdx.z ? part1 : part0;
  __shared__ __align__(16) unsigned short As[128 * 32];
  __shared__ __align__(16) unsigned short Bs[128 * 32];
  const int tid = threadIdx.x;
  const int s0 = tid, s1 = tid + 256;
  const int r0 = s0 >> 2, q0 = (s0 & 3) ^ ((r0 >> 1) & 3);
  const int r1 = s1 >> 2, q1 = (s1 & 3) ^ ((r1 >> 1) & 3);
  const unsigned short* aP0 = Ab + (size_t)(m0 + r0) * FF_ + q0 * 8 + k0;
  const unsigned short* aP1 = Ab + (size_t)(m0 + r1) * FF_ + q1 * 8 + k0;
  const unsigned short* bP0 = Bb + (size_t)(n0 + r0) * FF_ + q0 * 8 + k0;
  const unsigned short* bP1 = Bb + (size_t)(n0 + r1) * FF_ + q1 * 8 + k0;
  char* AsC = (char*)As;
  char* BsC = (char*)Bs;
  const int wave = tid >> 6, lane = tid & 63;
  const int wm0 = (wave >> 1) * 64, wn0 = (wave & 1) * 64;
  const int lr = lane & 15, lq = lane >> 4;
  int aoff[4], boff[4];
#pragma unroll
  for (int t = 0; t < 4; ++t) {
    aoff[t] = slot_of(wm0 + t * 16 + lr, lq) * 16;
    boff[t] = slot_of(wn0 + t * 16 + lr, lq) * 16;
  }
  f32x4 acc[4][4];
#pragma unroll
  for (int i = 0; i < 4; ++i)
#pragma unroll
    for (int j = 0; j < 4; ++j) acc[i][j] = (f32x4){0.f, 0.f, 0.f, 0.f};
  for (int kt = 0; kt < FF_ / 2; kt += 32) {
    __syncthreads();
    GLDS(aP0 + kt, AsC + s0 * 16);
    GLDS(aP1 + kt, AsC + s1 * 16);
    GLDS(bP0 + kt, BsC + s0 * 16);
    GLDS(bP1 + kt, BsC + s1 * 16);
    __syncthreads();
    bhalf8 af[4], bfr[4];
#pragma unroll
    for (int t = 0; t < 4; ++t) af[t] = *(const bhalf8*)(AsC + aoff[t]);
#pragma unroll
    for (int t = 0; t < 4; ++t) bfr[t] = *(const bhalf8*)(BsC + boff[t]);
#pragma unroll
    for (int i = 0; i < 4; ++i)
#pragma unroll
      for (int j = 0; j < 4; ++j)
        acc[i][j] = __builtin_amdgcn_mfma_f32_16x16x32_bf16(af[i], bfr[j], acc[i][j], 0, 0, 0);
  }
#pragma unroll
  for (int mt = 0; mt < 4; ++mt)
#pragma unroll
    for (int nt = 0; nt < 4; ++nt) {
      const f32x4 c = acc[mt][nt];
      const int col = n0 + wn0 + nt * 16 + lr;
#pragma unroll
      for (int r = 0; r < 4; ++r) {
        const int row = m0 + wm0 + mt * 16 + lq * 4 + r;
        part[(size_t)row * D_ + col] = c[r];
      }
    }
}

// ---------------- y += p0 + p1 (float4 per thread) --------------------------
__global__ __launch_bounds__(256) void add3_kernel(float* __restrict__ y,
    const float* __restrict__ p0, const float* __restrict__ p1) {
  const size_t i = (size_t)blockIdx.x * 256 + threadIdx.x;
  const float4 a = ((const float4*)y)[i];
  const float4 u = ((const float4*)p0)[i];
  const float4 v = ((const float4*)p1)[i];
  float4 o;
  o.x = a.x + u.x + v.x;
  o.y = a.y + u.y + v.y;
  o.z = a.z + u.z + v.z;
  o.w = a.w + u.w + v.w;
  ((float4*)y)[i] = o;
}

// ------- bf16 in-place slot0 += slot1 for 3 regions spaced 2*SZ -------------
__global__ __launch_bounds__(256) void add2b3_kernel(unsigned short* __restrict__ base) {
  const int reg = blockIdx.x >> 11;             // 2048 blocks per region
  const int ib = blockIdx.x & 2047;
  unsigned short* a = base + (size_t)reg * 2 * SZ_;
  const unsigned short* b = a + SZ_;
  const size_t i = (size_t)ib * 256 + threadIdx.x;
  uint4 av = ((uint4*)a)[i];
  const uint4 bv = ((const uint4*)b)[i];
  av.x = addpair_bf(av.x, bv.x);
  av.y = addpair_bf(av.y, bv.y);
  av.z = addpair_bf(av.z, bv.z);
  av.w = addpair_bf(av.w, bv.w);
  ((uint4*)a)[i] = av;
}

// ---------------- Flash attention (MFMA bf16, fp32 softmax) -----------------
__global__ __launch_bounds__(256) void attn_kernel(const unsigned short* __restrict__ q,
    const unsigned short* __restrict__ k, const unsigned short* __restrict__ v,
    unsigned short* __restrict__ out) {
  const int bh = blockIdx.x;
  const int b = bh >> 4, h = bh & 15;
  const int q0 = blockIdx.y * 64;
  const int tid = threadIdx.x;
  const int wave = tid >> 6, lane = tid & 63;
  const int lc = lane & 15, lg = lane >> 4;

  __shared__ __align__(16) unsigned short Ks[64 * 64];   // [kv][d] swizzled
  __shared__ __align__(16) unsigned short Vt[64 * 64];   // [d][kv] swizzled
  __shared__ __align__(16) unsigned short Pl[4][16 * 64]; // per-wave [q][kv] swizzled
  char* const KsC = (char*)Ks;
  char* const VtC = (char*)Vt;
  char* const PlC = (char*)&Pl[wave][0];

  bhalf8 qf0, qf1;
  {
    const unsigned short* qp =
        q + ((size_t)(b * N_ + q0 + wave * 16 + lc)) * D_ + h * HD_ + lg * 8;
    qf0 = *(const bhalf8*)qp;
    qf1 = *(const bhalf8*)(qp + 32);
  }

  int off[4][2];
#pragma unroll
  for (int t = 0; t < 4; ++t)
#pragma unroll
    for (int ch = 0; ch < 2; ++ch)
      off[t][ch] = (t * 16 + lc) * 128 + (((ch * 4 + lg) ^ (lc & 7)) << 4);

  const int krow = tid >> 2, ks0 = tid & 3;
  const unsigned short* const kgp =
      k + ((size_t)(b * N_ + krow)) * D_ + h * HD_ + ks0 * 8;
  const int kwo0 = krow * 128 + ((ks0 ^ (krow & 7)) << 4);
  const int kwo1 = krow * 128 + (((ks0 ^ 4) ^ (krow & 7)) << 4);
  const int vkv = (tid & 31) * 2, vd0 = (tid >> 5) * 8;
  const unsigned short* const vgp =
      v + ((size_t)(b * N_ + vkv)) * D_ + h * HD_ + vd0;
  int vwo[8];
#pragma unroll
  for (int c = 0; c < 8; ++c) {
    const int d = vd0 + c;
    vwo[c] = d * 128 + ((((vkv >> 3) ^ (d & 7)) << 4)) + (vkv & 7) * 2;
  }

  float m_i[4], l_i[4];
  f32x4 o_acc[4];
#pragma unroll
  for (int r = 0; r < 4; ++r) { m_i[r] = -3.0e38f; l_i[r] = 0.f; }
#pragma unroll
  for (int t = 0; t < 4; ++t) o_acc[t] = (f32x4){0.f, 0.f, 0.f, 0.f};

  uint4 ka = *(const uint4*)(kgp);
  uint4 kb = *(const uint4*)(kgp + 32);
  uint4 va = *(const uint4*)(vgp);
  uint4 vb = *(const uint4*)(vgp + D_);

  for (int kt = 0; kt < 16; ++kt) {
    __syncthreads();
    *(uint4*)(KsC + kwo0) = ka;
    *(uint4*)(KsC + kwo1) = kb;
    {
      const unsigned av4[4] = {va.x, va.y, va.z, va.w};
      const unsigned bv4[4] = {vb.x, vb.y, vb.z, vb.w};
#pragma unroll
      for (int c = 0; c < 4; ++c) {
        const unsigned w0 = (av4[c] & 0xffffu) | (bv4[c] << 16);
        const unsigned w1 = (av4[c] >> 16) | (bv4[c] & 0xffff0000u);
        *(unsigned*)(VtC + vwo[2 * c]) = w0;
        *(unsigned*)(VtC + vwo[2 * c + 1]) = w1;
      }
    }
    __syncthreads();
    if (kt < 15) {
      const size_t go = (size_t)(kt + 1) * 64 * D_;
      ka = *(const uint4*)(kgp + go);
      kb = *(const uint4*)(kgp + go + 32);
      va = *(const uint4*)(vgp + go);
      vb = *(const uint4*)(vgp + go + D_);
    }
    f32x4 s4[4];
#pragma unroll
    for (int t = 0; t < 4; ++t) {
      f32x4 acc = (f32x4){0.f, 0.f, 0.f, 0.f};
      acc = __builtin_amdgcn_mfma_f32_16x16x32_bf16(
          qf0, *(const bhalf8*)(KsC + off[t][0]), acc, 0, 0, 0);
      acc = __builtin_amdgcn_mfma_f32_16x16x32_bf16(
          qf1, *(const bhalf8*)(KsC + off[t][1]), acc, 0, 0, 0);
      s4[t] = acc;
    }
    float alpha[4];
#pragma unroll
    for (int r = 0; r < 4; ++r) {
      const float e0 = s4[0][r] * 0.125f, e1 = s4[1][r] * 0.125f;
      const float e2 = s4[2][r] * 0.125f, e3 = s4[3][r] * 0.125f;
      float mt = fmaxf(fmaxf(e0, e1), fmaxf(e2, e3));
#pragma unroll
      for (int o = 8; o > 0; o >>= 1) mt = fmaxf(mt, __shfl_xor(mt, o));
      const float mn = fmaxf(m_i[r], mt);
      alpha[r] = __expf(m_i[r] - mn);
      m_i[r] = mn;
      const float p0 = __expf(e0 - mn), p1 = __expf(e1 - mn);
      const float p2 = __expf(e2 - mn), p3 = __expf(e3 - mn);
      float rs = p0 + p1 + p2 + p3;
#pragma unroll
      for (int o = 8; o > 0; o >>= 1) rs += __shfl_xor(rs, o);
      l_i[r] = l_i[r] * alpha[r] + rs;
      const int qrow = 4 * lg + r;
      const int rb = qrow * 128 + (lc & 7) * 2;
      const int sw = qrow & 7;
      *(unsigned short*)(PlC + rb + (((0 + (lc >> 3)) ^ sw) << 4)) = f2bf(p0);
      *(unsigned short*)(PlC + rb + (((2 + (lc >> 3)) ^ sw) << 4)) = f2bf(p1);
      *(unsigned short*)(PlC + rb + (((4 + (lc >> 3)) ^ sw) << 4)) = f2bf(p2);
      *(unsigned short*)(PlC + rb + (((6 + (lc >> 3)) ^ sw) << 4)) = f2bf(p3);
    }
#pragma unroll
    for (int t = 0; t < 4; ++t) {
      f32x4 o = o_acc[t];
      o[0] *= alpha[0]; o[1] *= alpha[1]; o[2] *= alpha[2]; o[3] *= alpha[3];
      o_acc[t] = o;
    }
    const bhalf8 pf0 = *(const bhalf8*)(PlC + off[0][0]);
    const bhalf8 pf1 = *(const bhalf8*)(PlC + off[0][1]);
#pragma unroll
    for (int t = 0; t < 4; ++t) {
      o_acc[t] = __builtin_amdgcn_mfma_f32_16x16x32_bf16(
          pf0, *(const bhalf8*)(VtC + off[t][0]), o_acc[t], 0, 0, 0);
      o_acc[t] = __builtin_amdgcn_mfma_f32_16x16x32_bf16(
          pf1, *(const bhalf8*)(VtC + off[t][1]), o_acc[t], 0, 0, 0);
    }
  }
  const size_t obase = ((size_t)(b * N_ + q0 + wave * 16)) * D_ + h * HD_;
#pragma unroll
  for (int r = 0; r < 4; ++r) {
    const float inv = 1.f / l_i[r];
    const size_t rbase = obase + (size_t)(4 * lg + r) * D_;
#pragma unroll
    for (int t = 0; t < 4; ++t)
      out[rbase + t * 16 + lc] = f2bf(o_acc[t][r] * inv);
  }
}

// ---------------- load-balance scalar ---------------------------------------
__global__ void lb_kernel(const int* __restrict__ ecnt,
                          const float* __restrict__ psum, float* __restrict__ out) {
  if (threadIdx.x == 0 && blockIdx.x == 0) {
    float tot = 0.f;
    for (int e = 0; e < E_; ++e) tot += (float)ecnt[e];
    float s = 0.f;
    for (int e = 0; e < E_; ++e) s += (float)ecnt[e] / (tot + 1e-6f) * psum[e];
    out[0] = s * (float)E_;
  }
}

extern "C" void kernel_launch(void* const* d_in, const int* in_sizes, int n_in,
                              void* d_out, int out_size, void* d_ws, size_t ws_size,
                              hipStream_t stream) {
  (void)in_sizes; (void)n_in; (void)out_size;
  const float* x  = (const float*)d_in[0];
  const float* Wr = (const float*)d_in[1];
  const float* Wq = (const float*)d_in[2];
  const float* Wk = (const float*)d_in[3];
  const float* Wv = (const float*)d_in[4];
  const float* Wo = (const float*)d_in[5];
  const float* W1 = (const float*)d_in[6];
  const float* b1 = (const float*)d_in[7];
  const float* W2 = (const float*)d_in[8];
  const float* b2 = (const float*)d_in[9];
  const float* g1 = (const float*)d_in[10];
  const float* be1 = (const float*)d_in[11];
  const float* g2 = (const float*)d_in[12];
  const float* be2 = (const float*)d_in[13];
  float* y = (float*)d_out;

  // ---- workspace layout --------------------------------------------------
  // big path (>=136MB): Rb3 [0,72MB) holds Wq|Wk|Wv bf16 for ONE fused qkv
  //   moe dispatch (3x active blocks); after it, Wo->[0,24), W1b->[24,32),
  //   W2b->[32,40), midb->[40,72) overlay the dead regions.
  // small path: exact R3 96.6MB layout (per-weight serial cvtw+moe).
  const bool big = ws_size >= (size_t)136 * 1024 * 1024;
  char* p = (char*)d_ws;
  unsigned short *Rb, *xnb, *q2b, *WoB, *W1b, *W2b, *midb;
  char* tail;
  if (big) {
    Rb  = (unsigned short*)p;                              // 72 MB (3 expert sets)
    xnb = (unsigned short*)(p + 75497472);                 // 8 MB
    q2b = (unsigned short*)(p + 75497472 + 8388608);       // 48 MB (q|k|v, 2 slots each)
    tail = p + 75497472 + 8388608 + 6 * SZ_ * 2;
    WoB  = Rb;                                             // after fused moe
    W1b  = (unsigned short*)(p + 25165824);
    W2b  = (unsigned short*)(p + 33554432);
    midb = (unsigned short*)(p + 41943040);                // 32 MB
  } else {
    Rb  = (unsigned short*)p;                              // 24 MB (1 expert set)
    xnb = (unsigned short*)(p + 25165824);
    q2b = xnb + SZ_;
    W1b = q2b + 6 * SZ_;
    W2b = W1b + (size_t)FF_ * D_;
    tail = (char*)(W2b + (size_t)FF_ * D_);
    WoB  = Rb;
    midb = (unsigned short*)d_ws;                          // 32 MB over Rb+xnb
  }
  unsigned short* k2b = q2b + 2 * SZ_;
  unsigned short* v2b = k2b + 2 * SZ_;
  float* psum = (float*)tail;            tail += E_ * 4;
  int* ecnt = (int*)tail;                tail += E_ * 4;
  int* etok = (int*)tail;                tail += (size_t)E_ * T_ * 4;
  float* ewt = (float*)tail;             tail += (size_t)E_ * T_ * 4;
  float* probs = (float*)tail;           tail += (size_t)T_ * E_ * 4;
  int* topi = (int*)tail;                tail += T_ * 4;
  float2* topw = (float2*)tail;
  // overlays (dead at time of reuse):
  unsigned short* attb = v2b + SZ_;      // attn out (v slot1 dead after add2b3)
  unsigned short* o2b  = q2b;            // o-proj 2 slots (q dead post-attn)
  unsigned short* hnb  = v2b;            // hn bf16 (v slot0 dead post-attn)
  float* part0         = (float*)k2b;    // ffn2 partial z=0 (k dead post-attn)
  float* part1         = (float*)v2b;    // ffn2 partial z=1 (v dead post-ffn1)

  const int gw = (E_ * D_ * D_) / 1024;
  // 1. LN1 (bf16) + router (fused LN fp32) + lists
  ln_kernel<<<T_, 256, 0, stream>>>(x, g1, be1, xnb);
  router_ln<<<T_, 256, 0, stream>>>(x, g1, be1, Wr, probs, topi, topw);
  psum_kernel<<<1, 256, 0, stream>>>(probs, psum);
  build_lists<<<E_, 256, 0, stream>>>(topi, topw, ecnt, etok, ewt);
  // 2. MoE q,k,v projections
  if (big) {
    cvtw3_kernel<<<3 * gw, 256, 0, stream>>>(Wq, Wk, Wv, Rb);
    moe_mfma<<<dim3(24, T_ / 128, E_), 256, 0, stream>>>(xnb, Rb, q2b, ecnt, etok, ewt);
    cvtw_kernel<<<gw, 256, 0, stream>>>(Wo, WoB);
    cvtw_kernel<<<(FF_ * D_) / 1024, 256, 0, stream>>>(W1, W1b);
    cvtw_kernel<<<(FF_ * D_) / 1024, 256, 0, stream>>>(W2, W2b);
  } else {
    cvtw_kernel<<<(FF_ * D_) / 1024, 256, 0, stream>>>(W1, W1b);
    cvtw_kernel<<<(FF_ * D_) / 1024, 256, 0, stream>>>(W2, W2b);
    cvtw_kernel<<<gw, 256, 0, stream>>>(Wq, Rb);
    moe_mfma<<<dim3(8, T_ / 128, E_), 256, 0, stream>>>(xnb, Rb, q2b, ecnt, etok, ewt);
    cvtw_kernel<<<gw, 256, 0, stream>>>(Wk, Rb);
    moe_mfma<<<dim3(8, T_ / 128, E_), 256, 0, stream>>>(xnb, Rb, k2b, ecnt, etok, ewt);
    cvtw_kernel<<<gw, 256, 0, stream>>>(Wv, Rb);
    moe_mfma<<<dim3(8, T_ / 128, E_), 256, 0, stream>>>(xnb, Rb, v2b, ecnt, etok, ewt);
    cvtw_kernel<<<gw, 256, 0, stream>>>(Wo, Rb);
  }
  // 3. Combine expert slots (bf16, one dispatch over q/k/v regions)
  add2b3_kernel<<<3 * (SZ_ / 2048), 256, 0, stream>>>(q2b);
  // 4. Attention (MFMA flash; out -> v2b slot1)
  attn_kernel<<<dim3(B_ * H_, N_ / 64), 256, 0, stream>>>(q2b, k2b, v2b, attb);
  // 5. Output projection (2 slots into o2b = q2b)
  moe_mfma<<<dim3(8, T_ / 128, E_), 256, 0, stream>>>(attb, WoB, o2b, ecnt, etok, ewt);
  // 6. h = x + o0 + o1 ; y = h + b2 (ffn2 pre-init) ; hn = LN2(h)
  hln2_kernel<<<T_, 256, 0, stream>>>(x, o2b, o2b + SZ_, g2, be2, b2, y, hnb);
  // 7. FFN (MFMA; ffn2 split-K=2 into fp32 partials, then combine)
  ffn1_mfma<<<dim3(FF_ / 128, T_ / 128), 256, 0, stream>>>(hnb, W1b, b1, midb);
  ffn2_split<<<dim3(D_ / 128, T_ / 128, 2), 256, 0, stream>>>(midb, W2b, part0, part1);
  add3_kernel<<<SZ_ / 1024, 256, 0, stream>>>(y, part0, part1);
  // 8. load-balance scalar
  lb_kernel<<<1, 64, 0, stream>>>(ecnt, psum, y + SZ_);
}

// Round 6
// 624.401 us; speedup vs baseline: 1.1511x; 1.0053x over previous
//
#include <hip/hip_runtime.h>

#define B_ 4
#define N_ 1024
#define D_ 1024
#define H_ 16
#define HD_ 64
#define E_ 12
#define T_ 4096
#define FF_ 4096

static constexpr size_t SZ_ = (size_t)T_ * D_;

typedef __attribute__((ext_vector_type(8))) short bhalf8;
typedef __attribute__((ext_vector_type(4))) float f32x4;

#define GLDS(gp, lp)                                                         \
  __builtin_amdgcn_global_load_lds(                                          \
      (const __attribute__((address_space(1))) void*)(gp),                   \
      (__attribute__((address_space(3))) void*)(lp), 16, 0, 0)

__device__ __forceinline__ float wave_sum64(float v) {
#pragma unroll
  for (int o = 32; o > 0; o >>= 1) v += __shfl_down(v, o);
  return v;
}

__device__ __forceinline__ unsigned short f2bf(float f) {
  unsigned u = __float_as_uint(f);
  u += 0x7FFFu + ((u >> 16) & 1u);
  return (unsigned short)(u >> 16);
}
__device__ __forceinline__ float b2f(unsigned short s) {
  return __uint_as_float(((unsigned)s) << 16);
}
__device__ __forceinline__ unsigned addpair_bf(unsigned x, unsigned y) {
  float lo = b2f((unsigned short)(x & 0xffff)) + b2f((unsigned short)(y & 0xffff));
  float hi = b2f((unsigned short)(x >> 16)) + b2f((unsigned short)(y >> 16));
  return (unsigned)f2bf(lo) | ((unsigned)f2bf(hi) << 16);
}

__device__ __forceinline__ float gelu_f(float x) {
  float u = 0.7978845608028654f * (x + 0.044715f * x * x * x);
  u = fminf(fmaxf(u, -15.f), 15.f);
  float e = __expf(2.f * u);
  float th = (e - 1.f) / (e + 1.f);
  return 0.5f * x * (1.f + th);
}

// swizzled LDS slot for (row, kseg): keeps glds lane-contiguity AND 2-way-max
// bank aliasing on ds_read_b128 frag reads
__device__ __forceinline__ int slot_of(int row, int q) {
  return row * 4 + (q ^ ((row >> 1) & 3));
}

// ---------------- LayerNorm: bf16 out only ----------------------------------
__global__ __launch_bounds__(256) void ln_kernel(const float* __restrict__ x,
    const float* __restrict__ g, const float* __restrict__ b,
    unsigned short* __restrict__ outb) {
  const int t = blockIdx.x, tid = threadIdx.x;
  const size_t base = (size_t)t * D_;
  const float4 v = ((const float4*)(x + base))[tid];
  float s = v.x + v.y + v.z + v.w;
  float s2 = v.x * v.x + v.y * v.y + v.z * v.z + v.w * v.w;
  s = wave_sum64(s);
  s2 = wave_sum64(s2);
  __shared__ float ls[4], ls2[4];
  const int w = tid >> 6;
  if ((tid & 63) == 0) { ls[w] = s; ls2[w] = s2; }
  __syncthreads();
  const float mean = (ls[0] + ls[1] + ls[2] + ls[3]) * (1.0f / D_);
  const float var = (ls2[0] + ls2[1] + ls2[2] + ls2[3]) * (1.0f / D_) - mean * mean;
  const float inv = rsqrtf(var + 1e-5f);
  const float4 gg = ((const float4*)g)[tid];
  const float4 bb = ((const float4*)b)[tid];
  ushort4 u4;
  u4.x = f2bf((v.x - mean) * inv * gg.x + bb.x);
  u4.y = f2bf((v.y - mean) * inv * gg.y + bb.y);
  u4.z = f2bf((v.z - mean) * inv * gg.z + bb.z);
  u4.w = f2bf((v.w - mean) * inv * gg.w + bb.w);
  ((ushort4*)(outb + base))[tid] = u4;
}

// ---- h = x + o0 + o1; y = h + b2 (fp32, pre-init for ffn2); hn bf16 --------
__global__ __launch_bounds__(256) void hln2_kernel(const float* __restrict__ x,
    const unsigned short* __restrict__ oa, const unsigned short* __restrict__ ob,
    const float* __restrict__ g, const float* __restrict__ be,
    const float* __restrict__ b2, float* __restrict__ y,
    unsigned short* __restrict__ hnb) {
  const int t = blockIdx.x, tid = threadIdx.x;
  const size_t base = (size_t)t * D_;
  const float4 xv = ((const float4*)(x + base))[tid];
  const ushort4 av = ((const ushort4*)(oa + base))[tid];
  const ushort4 bv = ((const ushort4*)(ob + base))[tid];
  float4 hv;
  hv.x = xv.x + b2f(av.x) + b2f(bv.x);
  hv.y = xv.y + b2f(av.y) + b2f(bv.y);
  hv.z = xv.z + b2f(av.z) + b2f(bv.z);
  hv.w = xv.w + b2f(av.w) + b2f(bv.w);
  const float4 b2v = ((const float4*)b2)[tid];
  float4 yv;
  yv.x = hv.x + b2v.x; yv.y = hv.y + b2v.y;
  yv.z = hv.z + b2v.z; yv.w = hv.w + b2v.w;
  ((float4*)(y + base))[tid] = yv;
  float s = hv.x + hv.y + hv.z + hv.w;
  float s2 = hv.x * hv.x + hv.y * hv.y + hv.z * hv.z + hv.w * hv.w;
  s = wave_sum64(s);
  s2 = wave_sum64(s2);
  __shared__ float ls[4], ls2[4];
  const int w = tid >> 6;
  if ((tid & 63) == 0) { ls[w] = s; ls2[w] = s2; }
  __syncthreads();
  const float mean = (ls[0] + ls[1] + ls[2] + ls[3]) * (1.0f / D_);
  const float var = (ls2[0] + ls2[1] + ls2[2] + ls2[3]) * (1.0f / D_) - mean * mean;
  const float inv = rsqrtf(var + 1e-5f);
  const float4 gg = ((const float4*)g)[tid];
  const float4 bb = ((const float4*)be)[tid];
  ushort4 o4;
  o4.x = f2bf((hv.x - mean) * inv * gg.x + bb.x);
  o4.y = f2bf((hv.y - mean) * inv * gg.y + bb.y);
  o4.z = f2bf((hv.z - mean) * inv * gg.z + bb.z);
  o4.w = f2bf((hv.w - mean) * inv * gg.w + bb.w);
  ((ushort4*)(hnb + base))[tid] = o4;
}

// ------- Router fused with LN1 (fp32 path, deterministic selection) ---------
__global__ __launch_bounds__(256) void router_ln(const float* __restrict__ x,
    const float* __restrict__ g, const float* __restrict__ b,
    const float* __restrict__ Wr, float* __restrict__ probs,
    int* __restrict__ topi, float2* __restrict__ topw) {
  const int t = blockIdx.x, tid = threadIdx.x;
  const float4 xv = ((const float4*)(x + (size_t)t * D_))[tid];
  float s = xv.x + xv.y + xv.z + xv.w;
  float s2 = xv.x * xv.x + xv.y * xv.y + xv.z * xv.z + xv.w * xv.w;
  s = wave_sum64(s);
  s2 = wave_sum64(s2);
  __shared__ float ls[4], ls2[4];
  const int w = tid >> 6;
  if ((tid & 63) == 0) { ls[w] = s; ls2[w] = s2; }
  __syncthreads();
  const float mean = (ls[0] + ls[1] + ls[2] + ls[3]) * (1.0f / D_);
  const float var = (ls2[0] + ls2[1] + ls2[2] + ls2[3]) * (1.0f / D_) - mean * mean;
  const float inv = rsqrtf(var + 1e-5f);
  const float4 gg = ((const float4*)g)[tid];
  const float4 bb = ((const float4*)b)[tid];
  float4 xn4;
  xn4.x = (xv.x - mean) * inv * gg.x + bb.x;
  xn4.y = (xv.y - mean) * inv * gg.y + bb.y;
  xn4.z = (xv.z - mean) * inv * gg.z + bb.z;
  xn4.w = (xv.w - mean) * inv * gg.w + bb.w;
  float acc[E_];
#pragma unroll
  for (int e = 0; e < E_; ++e) {
    const float4 wv = ((const float4*)(Wr + (size_t)e * D_))[tid];
    acc[e] = xn4.x * wv.x + xn4.y * wv.y + xn4.z * wv.z + xn4.w * wv.w;
  }
#pragma unroll
  for (int e = 0; e < E_; ++e) acc[e] = wave_sum64(acc[e]);
  __shared__ float red[4][E_];
  if ((tid & 63) == 0) {
#pragma unroll
    for (int e = 0; e < E_; ++e) red[w][e] = acc[e];
  }
  __syncthreads();
  if (tid == 0) {
    float lg[E_];
    float mx = -1e30f;
#pragma unroll
    for (int e = 0; e < E_; ++e) {
      lg[e] = red[0][e] + red[1][e] + red[2][e] + red[3][e];
      mx = fmaxf(mx, lg[e]);
    }
    float p[E_];
    float sum = 0.f;
#pragma unroll
    for (int e = 0; e < E_; ++e) { p[e] = __expf(lg[e] - mx); sum += p[e]; }
    const float invs = 1.f / sum;
#pragma unroll
    for (int e = 0; e < E_; ++e) {
      p[e] *= invs;
      probs[t * E_ + e] = p[e];
    }
    int i0 = 0;
#pragma unroll
    for (int e = 1; e < E_; ++e) if (p[e] > p[i0]) i0 = e;
    int i1 = (i0 == 0) ? 1 : 0;
#pragma unroll
    for (int e = 0; e < E_; ++e) if (e != i0 && p[e] > p[i1]) i1 = e;
    const float rs = 1.f / (p[i0] + p[i1] + 1e-6f);
    topi[t] = i0 | (i1 << 8);
    topw[t] = make_float2(p[i0] * rs, p[i1] * rs);
  }
}

__global__ __launch_bounds__(256) void psum_kernel(const float* __restrict__ probs,
                                                   float* __restrict__ psum) {
  const int tid = threadIdx.x;
  float local[E_] = {};
  for (int t = tid; t < T_; t += 256) {
#pragma unroll
    for (int e = 0; e < E_; ++e) local[e] += probs[t * E_ + e];
  }
#pragma unroll
  for (int e = 0; e < E_; ++e) local[e] = wave_sum64(local[e]);
  __shared__ float red[4][E_];
  const int w = tid >> 6;
  if ((tid & 63) == 0) {
#pragma unroll
    for (int e = 0; e < E_; ++e) red[w][e] = local[e];
  }
  __syncthreads();
  if (tid < E_)
    psum[tid] = red[0][tid] + red[1][tid] + red[2][tid] + red[3][tid];
}

__global__ __launch_bounds__(256) void build_lists(const int* __restrict__ topi,
    const float2* __restrict__ topw, int* __restrict__ ecnt,
    int* __restrict__ etok, float* __restrict__ ewt) {
  const int e = blockIdx.x;
  const int tid = threadIdx.x;
  const int wid = tid >> 6, lane = tid & 63;
  __shared__ int wbase[4];
  __shared__ int base;
  if (tid == 0) base = 0;
  __syncthreads();
  for (int c = 0; c < T_; c += 256) {
    const int t = c + tid;
    const int pk = topi[t];
    const int i0 = pk & 0xFF, i1 = (pk >> 8) & 0xFF;
    const float2 w2 = topw[t];
    const int sel = (i0 == e) ? 0 : ((i1 == e) ? 1 : -1);
    const unsigned long long mask = __ballot(sel >= 0);
    const int prefix = __popcll(mask & ((1ULL << lane) - 1ULL));
    if (lane == 0) wbase[wid] = __popcll(mask);
    __syncthreads();
    if (tid == 0) {
      int s = base;
#pragma unroll
      for (int ww = 0; ww < 4; ++ww) { int cc = wbase[ww]; wbase[ww] = s; s += cc; }
      base = s;
    }
    __syncthreads();
    if (sel >= 0) {
      const int pos = wbase[wid] + prefix;
      etok[e * T_ + pos] = t | (sel << 16);
      ewt[e * T_ + pos] = sel ? w2.y : w2.x;
    }
    __syncthreads();
  }
  if (tid == 0) ecnt[e] = base;
}

// -------- fp32 -> bf16 weight conversion (float4 per thread) ----------------
__global__ __launch_bounds__(256) void cvtw_kernel(const float* __restrict__ src,
    unsigned short* __restrict__ dst) {
  const size_t i = (size_t)blockIdx.x * 256 + threadIdx.x;
  const float4 v = ((const float4*)src)[i];
  ushort4 o;
  o.x = f2bf(v.x); o.y = f2bf(v.y); o.z = f2bf(v.z); o.w = f2bf(v.w);
  ((ushort4*)dst)[i] = o;
}

// -------- 3-source weight conversion into contiguous dst regions ------------
__global__ __launch_bounds__(256) void cvtw3_kernel(const float* __restrict__ a,
    const float* __restrict__ b, const float* __restrict__ c,
    unsigned short* __restrict__ dst) {
  const int gw = (E_ * D_ * D_) / 1024;
  const int r = blockIdx.x / gw;
  const int ib = blockIdx.x - r * gw;
  const float* src = (r == 0) ? a : ((r == 1) ? b : c);
  const size_t i = (size_t)ib * 256 + threadIdx.x;
  const float4 v = ((const float4*)src)[i];
  ushort4 o;
  o.x = f2bf(v.x); o.y = f2bf(v.y); o.z = f2bf(v.z); o.w = f2bf(v.w);
  ((ushort4*)(dst + (size_t)r * E_ * D_ * D_))[i] = o;
}

// ===== GEMM K-loop: T3 minimum-2-phase (LDS dbuf, prefetch-issue-early, =====
// ===== ONE vmcnt(0)+barrier per k-step via __syncthreads), T5 setprio.  =====

// ------- MoE gathered MFMA GEMM: A bf16 (glds gather), B bf16 (glds) --------
// blockIdx.x encodes (proj, n-block): proj = bx>>3 selects weight set / output.
__global__ __launch_bounds__(256) void moe_mfma(const unsigned short* __restrict__ Ab,
    const unsigned short* __restrict__ Wb, unsigned short* __restrict__ outb,
    const int* __restrict__ ecnt, const int* __restrict__ etok,
    const float* __restrict__ ewt) {
  const int e = blockIdx.z;
  const int Me = ecnt[e];
  const int m0 = blockIdx.y * 128;
  if (m0 >= Me) return;
  const int proj = blockIdx.x >> 3;
  const int n0 = (blockIdx.x & 7) * 128;
  const unsigned short* W = Wb + ((size_t)proj * E_ + e) * D_ * D_;
  unsigned short* out = outb + (size_t)proj * 2 * SZ_;
  __shared__ __align__(16) unsigned short As[2][128 * 32];
  __shared__ __align__(16) unsigned short Bs[2][128 * 32];
  __shared__ int stok[128];
  __shared__ float swt[128];
  const int tid = threadIdx.x;
  if (tid < 128) {
    const int s = m0 + tid;
    if (s < Me) { stok[tid] = etok[e * T_ + s]; swt[tid] = ewt[e * T_ + s]; }
    else        { stok[tid] = 0;                swt[tid] = 0.f; }
  }
  __syncthreads();
  const int s0 = tid, s1 = tid + 256;
  const int r0 = s0 >> 2, q0 = (s0 & 3) ^ ((r0 >> 1) & 3);
  const int r1 = s1 >> 2, q1 = (s1 & 3) ^ ((r1 >> 1) & 3);
  const unsigned short* aP0 = Ab + (size_t)(stok[r0] & 0xFFFF) * D_ + q0 * 8;
  const unsigned short* aP1 = Ab + (size_t)(stok[r1] & 0xFFFF) * D_ + q1 * 8;
  const unsigned short* bP0 = W + (size_t)(n0 + r0) * D_ + q0 * 8;
  const unsigned short* bP1 = W + (size_t)(n0 + r1) * D_ + q1 * 8;
  char* const A0 = (char*)As[0];
  char* const A1 = (char*)As[1];
  char* const B0 = (char*)Bs[0];
  char* const B1 = (char*)Bs[1];
  const int wave = tid >> 6, lane = tid & 63;
  const int wm0 = (wave >> 1) * 64, wn0 = (wave & 1) * 64;
  const int lr = lane & 15, lq = lane >> 4;
  int aoff[4], boff[4];
#pragma unroll
  for (int t = 0; t < 4; ++t) {
    aoff[t] = slot_of(wm0 + t * 16 + lr, lq) * 16;
    boff[t] = slot_of(wn0 + t * 16 + lr, lq) * 16;
  }
  f32x4 acc[4][4];
#pragma unroll
  for (int i = 0; i < 4; ++i)
#pragma unroll
    for (int j = 0; j < 4; ++j) acc[i][j] = (f32x4){0.f, 0.f, 0.f, 0.f};
  // prologue: stage k-tile 0 into buffer 0
  GLDS(aP0, A0 + s0 * 16);
  GLDS(aP1, A0 + s1 * 16);
  GLDS(bP0, B0 + s0 * 16);
  GLDS(bP1, B0 + s1 * 16);
  __syncthreads();
  for (int kt = 0; kt < D_; kt += 64) {
#pragma unroll
    for (int ph = 0; ph < 2; ++ph) {
      char* const cA = ph ? A1 : A0;
      char* const cB = ph ? B1 : B0;
      char* const nA = ph ? A0 : A1;
      char* const nB = ph ? B0 : B1;
      const int kn = kt + 32 + ph * 32;
      if (kn < D_) {
        GLDS(aP0 + kn, nA + s0 * 16);
        GLDS(aP1 + kn, nA + s1 * 16);
        GLDS(bP0 + kn, nB + s0 * 16);
        GLDS(bP1 + kn, nB + s1 * 16);
      }
      bhalf8 af[4], bfr[4];
#pragma unroll
      for (int t = 0; t < 4; ++t) af[t] = *(const bhalf8*)(cA + aoff[t]);
#pragma unroll
      for (int t = 0; t < 4; ++t) bfr[t] = *(const bhalf8*)(cB + boff[t]);
      __builtin_amdgcn_s_setprio(1);
#pragma unroll
      for (int i = 0; i < 4; ++i)
#pragma unroll
        for (int j = 0; j < 4; ++j)
          acc[i][j] = __builtin_amdgcn_mfma_f32_16x16x32_bf16(af[i], bfr[j], acc[i][j], 0, 0, 0);
      __builtin_amdgcn_s_setprio(0);
      __syncthreads();   // drains vmcnt(0): next buffer staged; cur readable next ph
    }
  }
#pragma unroll
  for (int mt = 0; mt < 4; ++mt)
#pragma unroll
    for (int nt = 0; nt < 4; ++nt) {
      const f32x4 c = acc[mt][nt];
      const int col = n0 + wn0 + nt * 16 + lr;
#pragma unroll
      for (int r = 0; r < 4; ++r) {
        const int row = wm0 + mt * 16 + lq * 4 + r;
        if (m0 + row < Me) {
          const int pk = stok[row];
          out[(size_t)(pk >> 16) * SZ_ + (size_t)(pk & 0xFFFF) * D_ + col] =
              f2bf(c[r] * swt[row]);
        }
      }
    }
}

// ------- FFN1 MFMA: midb = bf16(gelu(hnb @ W1b.T + b1)) ---------------------
__global__ __launch_bounds__(256) void ffn1_mfma(const unsigned short* __restrict__ Ab,
    const unsigned short* __restrict__ Bb, const float* __restrict__ bias,
    unsigned short* __restrict__ mid) {
  const int m0 = blockIdx.y * 128, n0 = blockIdx.x * 128;
  __shared__ __align__(16) unsigned short As[2][128 * 32];
  __shared__ __align__(16) unsigned short Bs[2][128 * 32];
  const int tid = threadIdx.x;
  const int s0 = tid, s1 = tid + 256;
  const int r0 = s0 >> 2, q0 = (s0 & 3) ^ ((r0 >> 1) & 3);
  const int r1 = s1 >> 2, q1 = (s1 & 3) ^ ((r1 >> 1) & 3);
  const unsigned short* aP0 = Ab + (size_t)(m0 + r0) * D_ + q0 * 8;
  const unsigned short* aP1 = Ab + (size_t)(m0 + r1) * D_ + q1 * 8;
  const unsigned short* bP0 = Bb + (size_t)(n0 + r0) * D_ + q0 * 8;
  const unsigned short* bP1 = Bb + (size_t)(n0 + r1) * D_ + q1 * 8;
  char* const A0 = (char*)As[0];
  char* const A1 = (char*)As[1];
  char* const B0 = (char*)Bs[0];
  char* const B1 = (char*)Bs[1];
  const int wave = tid >> 6, lane = tid & 63;
  const int wm0 = (wave >> 1) * 64, wn0 = (wave & 1) * 64;
  const int lr = lane & 15, lq = lane >> 4;
  int aoff[4], boff[4];
#pragma unroll
  for (int t = 0; t < 4; ++t) {
    aoff[t] = slot_of(wm0 + t * 16 + lr, lq) * 16;
    boff[t] = slot_of(wn0 + t * 16 + lr, lq) * 16;
  }
  f32x4 acc[4][4];
#pragma unroll
  for (int i = 0; i < 4; ++i)
#pragma unroll
    for (int j = 0; j < 4; ++j) acc[i][j] = (f32x4){0.f, 0.f, 0.f, 0.f};
  GLDS(aP0, A0 + s0 * 16);
  GLDS(aP1, A0 + s1 * 16);
  GLDS(bP0, B0 + s0 * 16);
  GLDS(bP1, B0 + s1 * 16);
  __syncthreads();
  for (int kt = 0; kt < D_; kt += 64) {
#pragma unroll
    for (int ph = 0; ph < 2; ++ph) {
      char* const cA = ph ? A1 : A0;
      char* const cB = ph ? B1 : B0;
      char* const nA = ph ? A0 : A1;
      char* const nB = ph ? B0 : B1;
      const int kn = kt + 32 + ph * 32;
      if (kn < D_) {
        GLDS(aP0 + kn, nA + s0 * 16);
        GLDS(aP1 + kn, nA + s1 * 16);
        GLDS(bP0 + kn, nB + s0 * 16);
        GLDS(bP1 + kn, nB + s1 * 16);
      }
      bhalf8 af[4], bfr[4];
#pragma unroll
      for (int t = 0; t < 4; ++t) af[t] = *(const bhalf8*)(cA + aoff[t]);
#pragma unroll
      for (int t = 0; t < 4; ++t) bfr[t] = *(const bhalf8*)(cB + boff[t]);
      __builtin_amdgcn_s_setprio(1);
#pragma unroll
      for (int i = 0; i < 4; ++i)
#pragma unroll
        for (int j = 0; j < 4; ++j)
          acc[i][j] = __builtin_amdgcn_mfma_f32_16x16x32_bf16(af[i], bfr[j], acc[i][j], 0, 0, 0);
      __builtin_amdgcn_s_setprio(0);
      __syncthreads();
    }
  }
  float bcol[4];
#pragma unroll
  for (int nt = 0; nt < 4; ++nt) bcol[nt] = bias[n0 + wn0 + nt * 16 + lr];
#pragma unroll
  for (int mt = 0; mt < 4; ++mt)
#pragma unroll
    for (int nt = 0; nt < 4; ++nt) {
      const f32x4 c = acc[mt][nt];
      const int col = n0 + wn0 + nt * 16 + lr;
#pragma unroll
      for (int r = 0; r < 4; ++r) {
        const int row = m0 + wm0 + mt * 16 + lq * 4 + r;
        mid[(size_t)row * FF_ + col] = f2bf(gelu_f(c[r] + bcol[nt]));
      }
    }
}

// ------- FFN2 split-K=2 MFMA: part[z] = midb[:, zK:(z+1)K] @ W2b[...].T -----
__global__ __launch_bounds__(256) void ffn2_split(const unsigned short* __restrict__ Ab,
    const unsigned short* __restrict__ Bb, float* __restrict__ part0,
    float* __restrict__ part1) {
  const int m0 = blockIdx.y * 128, n0 = blockIdx.x * 128;
  const int k0 = blockIdx.z * (FF_ / 2);
  float* const part = blockIdx.z ? part1 : part0;
  __shared__ __align__(16) unsigned short As[2][128 * 32];
  __shared__ __align__(16) unsigned short Bs[2][128 * 32];
  const int tid = threadIdx.x;
  const int s0 = tid, s1 = tid + 256;
  const int r0 = s0 >> 2, q0 = (s0 & 3) ^ ((r0 >> 1) & 3);
  const int r1 = s1 >> 2, q1 = (s1 & 3) ^ ((r1 >> 1) & 3);
  const unsigned short* aP0 = Ab + (size_t)(m0 + r0) * FF_ + q0 * 8 + k0;
  const unsigned short* aP1 = Ab + (size_t)(m0 + r1) * FF_ + q1 * 8 + k0;
  const unsigned short* bP0 = Bb + (size_t)(n0 + r0) * FF_ + q0 * 8 + k0;
  const unsigned short* bP1 = Bb + (size_t)(n0 + r1) * FF_ + q1 * 8 + k0;
  char* const A0 = (char*)As[0];
  char* const A1 = (char*)As[1];
  char* const B0 = (char*)Bs[0];
  char* const B1 = (char*)Bs[1];
  const int wave = tid >> 6, lane = tid & 63;
  const int wm0 = (wave >> 1) * 64, wn0 = (wave & 1) * 64;
  const int lr = lane & 15, lq = lane >> 4;
  int aoff[4], boff[4];
#pragma unroll
  for (int t = 0; t < 4; ++t) {
    aoff[t] = slot_of(wm0 + t * 16 + lr, lq) * 16;
    boff[t] = slot_of(wn0 + t * 16 + lr, lq) * 16;
  }
  f32x4 acc[4][4];
#pragma unroll
  for (int i = 0; i < 4; ++i)
#pragma unroll
    for (int j = 0; j < 4; ++j) acc[i][j] = (f32x4){0.f, 0.f, 0.f, 0.f};
  GLDS(aP0, A0 + s0 * 16);
  GLDS(aP1, A0 + s1 * 16);
  GLDS(bP0, B0 + s0 * 16);
  GLDS(bP1, B0 + s1 * 16);
  __syncthreads();
  for (int kt = 0; kt < FF_ / 2; kt += 64) {
#pragma unroll
    for (int ph = 0; ph < 2; ++ph) {
      char* const cA = ph ? A1 : A0;
      char* const cB = ph ? B1 : B0;
      char* const nA = ph ? A0 : A1;
      char* const nB = ph ? B0 : B1;
      const int kn = kt + 32 + ph * 32;
      if (kn < FF_ / 2) {
        GLDS(aP0 + kn, nA + s0 * 16);
        GLDS(aP1 + kn, nA + s1 * 16);
        GLDS(bP0 + kn, nB + s0 * 16);
        GLDS(bP1 + kn, nB + s1 * 16);
      }
      bhalf8 af[4], bfr[4];
#pragma unroll
      for (int t = 0; t < 4; ++t) af[t] = *(const bhalf8*)(cA + aoff[t]);
#pragma unroll
      for (int t = 0; t < 4; ++t) bfr[t] = *(const bhalf8*)(cB + boff[t]);
      __builtin_amdgcn_s_setprio(1);
#pragma unroll
      for (int i = 0; i < 4; ++i)
#pragma unroll
        for (int j = 0; j < 4; ++j)
          acc[i][j] = __builtin_amdgcn_mfma_f32_16x16x32_bf16(af[i], bfr[j], acc[i][j], 0, 0, 0);
      __builtin_amdgcn_s_setprio(0);
      __syncthreads();
    }
  }
#pragma unroll
  for (int mt = 0; mt < 4; ++mt)
#pragma unroll
    for (int nt = 0; nt < 4; ++nt) {
      const f32x4 c = acc[mt][nt];
      const int col = n0 + wn0 + nt * 16 + lr;
#pragma unroll
      for (int r = 0; r < 4; ++r) {
        const int row = m0 + wm0 + mt * 16 + lq * 4 + r;
        part[(size_t)row * D_ + col] = c[r];
      }
    }
}

// ---------------- y += p0 + p1 (float4 per thread) --------------------------
__global__ __launch_bounds__(256) void add3_kernel(float* __restrict__ y,
    const float* __restrict__ p0, const float* __restrict__ p1) {
  const size_t i = (size_t)blockIdx.x * 256 + threadIdx.x;
  const float4 a = ((const float4*)y)[i];
  const float4 u = ((const float4*)p0)[i];
  const float4 v = ((const float4*)p1)[i];
  float4 o;
  o.x = a.x + u.x + v.x;
  o.y = a.y + u.y + v.y;
  o.z = a.z + u.z + v.z;
  o.w = a.w + u.w + v.w;
  ((float4*)y)[i] = o;
}

// ------- bf16 in-place slot0 += slot1 for 3 regions spaced 2*SZ -------------
__global__ __launch_bounds__(256) void add2b3_kernel(unsigned short* __restrict__ base) {
  const int reg = blockIdx.x >> 11;             // 2048 blocks per region
  const int ib = blockIdx.x & 2047;
  unsigned short* a = base + (size_t)reg * 2 * SZ_;
  const unsigned short* b = a + SZ_;
  const size_t i = (size_t)ib * 256 + threadIdx.x;
  uint4 av = ((uint4*)a)[i];
  const uint4 bv = ((const uint4*)b)[i];
  av.x = addpair_bf(av.x, bv.x);
  av.y = addpair_bf(av.y, bv.y);
  av.z = addpair_bf(av.z, bv.z);
  av.w = addpair_bf(av.w, bv.w);
  ((uint4*)a)[i] = av;
}

// ---------------- Flash attention (MFMA bf16, fp32 softmax) -----------------
__global__ __launch_bounds__(256) void attn_kernel(const unsigned short* __restrict__ q,
    const unsigned short* __restrict__ k, const unsigned short* __restrict__ v,
    unsigned short* __restrict__ out) {
  const int bh = blockIdx.x;
  const int b = bh >> 4, h = bh & 15;
  const int q0 = blockIdx.y * 64;
  const int tid = threadIdx.x;
  const int wave = tid >> 6, lane = tid & 63;
  const int lc = lane & 15, lg = lane >> 4;

  __shared__ __align__(16) unsigned short Ks[64 * 64];   // [kv][d] swizzled
  __shared__ __align__(16) unsigned short Vt[64 * 64];   // [d][kv] swizzled
  __shared__ __align__(16) unsigned short Pl[4][16 * 64]; // per-wave [q][kv] swizzled
  char* const KsC = (char*)Ks;
  char* const VtC = (char*)Vt;
  char* const PlC = (char*)&Pl[wave][0];

  bhalf8 qf0, qf1;
  {
    const unsigned short* qp =
        q + ((size_t)(b * N_ + q0 + wave * 16 + lc)) * D_ + h * HD_ + lg * 8;
    qf0 = *(const bhalf8*)qp;
    qf1 = *(const bhalf8*)(qp + 32);
  }

  int off[4][2];
#pragma unroll
  for (int t = 0; t < 4; ++t)
#pragma unroll
    for (int ch = 0; ch < 2; ++ch)
      off[t][ch] = (t * 16 + lc) * 128 + (((ch * 4 + lg) ^ (lc & 7)) << 4);

  const int krow = tid >> 2, ks0 = tid & 3;
  const unsigned short* const kgp =
      k + ((size_t)(b * N_ + krow)) * D_ + h * HD_ + ks0 * 8;
  const int kwo0 = krow * 128 + ((ks0 ^ (krow & 7)) << 4);
  const int kwo1 = krow * 128 + (((ks0 ^ 4) ^ (krow & 7)) << 4);
  const int vkv = (tid & 31) * 2, vd0 = (tid >> 5) * 8;
  const unsigned short* const vgp =
      v + ((size_t)(b * N_ + vkv)) * D_ + h * HD_ + vd0;
  int vwo[8];
#pragma unroll
  for (int c = 0; c < 8; ++c) {
    const int d = vd0 + c;
    vwo[c] = d * 128 + ((((vkv >> 3) ^ (d & 7)) << 4)) + (vkv & 7) * 2;
  }

  float m_i[4], l_i[4];
  f32x4 o_acc[4];
#pragma unroll
  for (int r = 0; r < 4; ++r) { m_i[r] = -3.0e38f; l_i[r] = 0.f; }
#pragma unroll
  for (int t = 0; t < 4; ++t) o_acc[t] = (f32x4){0.f, 0.f, 0.f, 0.f};

  uint4 ka = *(const uint4*)(kgp);
  uint4 kb = *(const uint4*)(kgp + 32);
  uint4 va = *(const uint4*)(vgp);
  uint4 vb = *(const uint4*)(vgp + D_);

  for (int kt = 0; kt < 16; ++kt) {
    __syncthreads();
    *(uint4*)(KsC + kwo0) = ka;
    *(uint4*)(KsC + kwo1) = kb;
    {
      const unsigned av4[4] = {va.x, va.y, va.z, va.w};
      const unsigned bv4[4] = {vb.x, vb.y, vb.z, vb.w};
#pragma unroll
      for (int c = 0; c < 4; ++c) {
        const unsigned w0 = (av4[c] & 0xffffu) | (bv4[c] << 16);
        const unsigned w1 = (av4[c] >> 16) | (bv4[c] & 0xffff0000u);
        *(unsigned*)(VtC + vwo[2 * c]) = w0;
        *(unsigned*)(VtC + vwo[2 * c + 1]) = w1;
      }
    }
    __syncthreads();
    if (kt < 15) {
      const size_t go = (size_t)(kt + 1) * 64 * D_;
      ka = *(const uint4*)(kgp + go);
      kb = *(const uint4*)(kgp + go + 32);
      va = *(const uint4*)(vgp + go);
      vb = *(const uint4*)(vgp + go + D_);
    }
    f32x4 s4[4];
#pragma unroll
    for (int t = 0; t < 4; ++t) {
      f32x4 acc = (f32x4){0.f, 0.f, 0.f, 0.f};
      acc = __builtin_amdgcn_mfma_f32_16x16x32_bf16(
          qf0, *(const bhalf8*)(KsC + off[t][0]), acc, 0, 0, 0);
      acc = __builtin_amdgcn_mfma_f32_16x16x32_bf16(
          qf1, *(const bhalf8*)(KsC + off[t][1]), acc, 0, 0, 0);
      s4[t] = acc;
    }
    float alpha[4];
#pragma unroll
    for (int r = 0; r < 4; ++r) {
      const float e0 = s4[0][r] * 0.125f, e1 = s4[1][r] * 0.125f;
      const float e2 = s4[2][r] * 0.125f, e3 = s4[3][r] * 0.125f;
      float mt = fmaxf(fmaxf(e0, e1), fmaxf(e2, e3));
#pragma unroll
      for (int o = 8; o > 0; o >>= 1) mt = fmaxf(mt, __shfl_xor(mt, o));
      const float mn = fmaxf(m_i[r], mt);
      alpha[r] = __expf(m_i[r] - mn);
      m_i[r] = mn;
      const float p0 = __expf(e0 - mn), p1 = __expf(e1 - mn);
      const float p2 = __expf(e2 - mn), p3 = __expf(e3 - mn);
      float rs = p0 + p1 + p2 + p3;
#pragma unroll
      for (int o = 8; o > 0; o >>= 1) rs += __shfl_xor(rs, o);
      l_i[r] = l_i[r] * alpha[r] + rs;
      const int qrow = 4 * lg + r;
      const int rb = qrow * 128 + (lc & 7) * 2;
      const int sw = qrow & 7;
      *(unsigned short*)(PlC + rb + (((0 + (lc >> 3)) ^ sw) << 4)) = f2bf(p0);
      *(unsigned short*)(PlC + rb + (((2 + (lc >> 3)) ^ sw) << 4)) = f2bf(p1);
      *(unsigned short*)(PlC + rb + (((4 + (lc >> 3)) ^ sw) << 4)) = f2bf(p2);
      *(unsigned short*)(PlC + rb + (((6 + (lc >> 3)) ^ sw) << 4)) = f2bf(p3);
    }
#pragma unroll
    for (int t = 0; t < 4; ++t) {
      f32x4 o = o_acc[t];
      o[0] *= alpha[0]; o[1] *= alpha[1]; o[2] *= alpha[2]; o[3] *= alpha[3];
      o_acc[t] = o;
    }
    const bhalf8 pf0 = *(const bhalf8*)(PlC + off[0][0]);
    const bhalf8 pf1 = *(const bhalf8*)(PlC + off[0][1]);
#pragma unroll
    for (int t = 0; t < 4; ++t) {
      o_acc[t] = __builtin_amdgcn_mfma_f32_16x16x32_bf16(
          pf0, *(const bhalf8*)(VtC + off[t][0]), o_acc[t], 0, 0, 0);
      o_acc[t] = __builtin_amdgcn_mfma_f32_16x16x32_bf16(
          pf1, *(const bhalf8*)(VtC + off[t][1]), o_acc[t], 0, 0, 0);
    }
  }
  const size_t obase = ((size_t)(b * N_ + q0 + wave * 16)) * D_ + h * HD_;
#pragma unroll
  for (int r = 0; r < 4; ++r) {
    const float inv = 1.f / l_i[r];
    const size_t rbase = obase + (size_t)(4 * lg + r) * D_;
#pragma unroll
    for (int t = 0; t < 4; ++t)
      out[rbase + t * 16 + lc] = f2bf(o_acc[t][r] * inv);
  }
}

// ---------------- load-balance scalar ---------------------------------------
__global__ void lb_kernel(const int* __restrict__ ecnt,
                          const float* __restrict__ psum, float* __restrict__ out) {
  if (threadIdx.x == 0 && blockIdx.x == 0) {
    float tot = 0.f;
    for (int e = 0; e < E_; ++e) tot += (float)ecnt[e];
    float s = 0.f;
    for (int e = 0; e < E_; ++e) s += (float)ecnt[e] / (tot + 1e-6f) * psum[e];
    out[0] = s * (float)E_;
  }
}

extern "C" void kernel_launch(void* const* d_in, const int* in_sizes, int n_in,
                              void* d_out, int out_size, void* d_ws, size_t ws_size,
                              hipStream_t stream) {
  (void)in_sizes; (void)n_in; (void)out_size;
  const float* x  = (const float*)d_in[0];
  const float* Wr = (const float*)d_in[1];
  const float* Wq = (const float*)d_in[2];
  const float* Wk = (const float*)d_in[3];
  const float* Wv = (const float*)d_in[4];
  const float* Wo = (const float*)d_in[5];
  const float* W1 = (const float*)d_in[6];
  const float* b1 = (const float*)d_in[7];
  const float* W2 = (const float*)d_in[8];
  const float* b2 = (const float*)d_in[9];
  const float* g1 = (const float*)d_in[10];
  const float* be1 = (const float*)d_in[11];
  const float* g2 = (const float*)d_in[12];
  const float* be2 = (const float*)d_in[13];
  float* y = (float*)d_out;

  // ---- workspace layout --------------------------------------------------
  // big path (>=136MB): Rb3 [0,72MB) holds Wq|Wk|Wv bf16 for ONE fused qkv
  //   moe dispatch (3x active blocks); after it, Wo->[0,24), W1b->[24,32),
  //   W2b->[32,40), midb->[40,72) overlay the dead regions.
  // small path: 96.6MB layout (per-weight serial cvtw+moe).
  const bool big = ws_size >= (size_t)136 * 1024 * 1024;
  char* p = (char*)d_ws;
  unsigned short *Rb, *xnb, *q2b, *WoB, *W1b, *W2b, *midb;
  char* tail;
  if (big) {
    Rb  = (unsigned short*)p;                              // 72 MB (3 expert sets)
    xnb = (unsigned short*)(p + 75497472);                 // 8 MB
    q2b = (unsigned short*)(p + 75497472 + 8388608);       // 48 MB (q|k|v, 2 slots each)
    tail = p + 75497472 + 8388608 + 6 * SZ_ * 2;
    WoB  = Rb;                                             // after fused moe
    W1b  = (unsigned short*)(p + 25165824);
    W2b  = (unsigned short*)(p + 33554432);
    midb = (unsigned short*)(p + 41943040);                // 32 MB
  } else {
    Rb  = (unsigned short*)p;                              // 24 MB (1 expert set)
    xnb = (unsigned short*)(p + 25165824);
    q2b = xnb + SZ_;
    W1b = q2b + 6 * SZ_;
    W2b = W1b + (size_t)FF_ * D_;
    tail = (char*)(W2b + (size_t)FF_ * D_);
    WoB  = Rb;
    midb = (unsigned short*)d_ws;                          // 32 MB over Rb+xnb
  }
  unsigned short* k2b = q2b + 2 * SZ_;
  unsigned short* v2b = k2b + 2 * SZ_;
  float* psum = (float*)tail;            tail += E_ * 4;
  int* ecnt = (int*)tail;                tail += E_ * 4;
  int* etok = (int*)tail;                tail += (size_t)E_ * T_ * 4;
  float* ewt = (float*)tail;             tail += (size_t)E_ * T_ * 4;
  float* probs = (float*)tail;           tail += (size_t)T_ * E_ * 4;
  int* topi = (int*)tail;                tail += T_ * 4;
  float2* topw = (float2*)tail;
  // overlays (dead at time of reuse):
  unsigned short* attb = v2b + SZ_;      // attn out (v slot1 dead after add2b3)
  unsigned short* o2b  = q2b;            // o-proj 2 slots (q dead post-attn)
  unsigned short* hnb  = v2b;            // hn bf16 (v slot0 dead post-attn)
  float* part0         = (float*)k2b;    // ffn2 partial z=0 (k dead post-attn)
  float* part1         = (float*)v2b;    // ffn2 partial z=1 (v dead post-ffn1)

  const int gw = (E_ * D_ * D_) / 1024;
  // 1. LN1 (bf16) + router (fused LN fp32) + lists
  ln_kernel<<<T_, 256, 0, stream>>>(x, g1, be1, xnb);
  router_ln<<<T_, 256, 0, stream>>>(x, g1, be1, Wr, probs, topi, topw);
  psum_kernel<<<1, 256, 0, stream>>>(probs, psum);
  build_lists<<<E_, 256, 0, stream>>>(topi, topw, ecnt, etok, ewt);
  // 2. MoE q,k,v projections
  if (big) {
    cvtw3_kernel<<<3 * gw, 256, 0, stream>>>(Wq, Wk, Wv, Rb);
    moe_mfma<<<dim3(24, T_ / 128, E_), 256, 0, stream>>>(xnb, Rb, q2b, ecnt, etok, ewt);
    cvtw_kernel<<<gw, 256, 0, stream>>>(Wo, WoB);
    cvtw_kernel<<<(FF_ * D_) / 1024, 256, 0, stream>>>(W1, W1b);
    cvtw_kernel<<<(FF_ * D_) / 1024, 256, 0, stream>>>(W2, W2b);
  } else {
    cvtw_kernel<<<(FF_ * D_) / 1024, 256, 0, stream>>>(W1, W1b);
    cvtw_kernel<<<(FF_ * D_) / 1024, 256, 0, stream>>>(W2, W2b);
    cvtw_kernel<<<gw, 256, 0, stream>>>(Wq, Rb);
    moe_mfma<<<dim3(8, T_ / 128, E_), 256, 0, stream>>>(xnb, Rb, q2b, ecnt, etok, ewt);
    cvtw_kernel<<<gw, 256, 0, stream>>>(Wk, Rb);
    moe_mfma<<<dim3(8, T_ / 128, E_), 256, 0, stream>>>(xnb, Rb, k2b, ecnt, etok, ewt);
    cvtw_kernel<<<gw, 256, 0, stream>>>(Wv, Rb);
    moe_mfma<<<dim3(8, T_ / 128, E_), 256, 0, stream>>>(xnb, Rb, v2b, ecnt, etok, ewt);
    cvtw_kernel<<<gw, 256, 0, stream>>>(Wo, Rb);
  }
  // 3. Combine expert slots (bf16, one dispatch over q/k/v regions)
  add2b3_kernel<<<3 * (SZ_ / 2048), 256, 0, stream>>>(q2b);
  // 4. Attention (MFMA flash; out -> v2b slot1)
  attn_kernel<<<dim3(B_ * H_, N_ / 64), 256, 0, stream>>>(q2b, k2b, v2b, attb);
  // 5. Output projection (2 slots into o2b = q2b)
  moe_mfma<<<dim3(8, T_ / 128, E_), 256, 0, stream>>>(attb, WoB, o2b, ecnt, etok, ewt);
  // 6. h = x + o0 + o1 ; y = h + b2 (ffn2 pre-init) ; hn = LN2(h)
  hln2_kernel<<<T_, 256, 0, stream>>>(x, o2b, o2b + SZ_, g2, be2, b2, y, hnb);
  // 7. FFN (MFMA; ffn2 split-K=2 into fp32 partials, then combine)
  ffn1_mfma<<<dim3(FF_ / 128, T_ / 128), 256, 0, stream>>>(hnb, W1b, b1, midb);
  ffn2_split<<<dim3(D_ / 128, T_ / 128, 2), 256, 0, stream>>>(midb, W2b, part0, part1);
  add3_kernel<<<SZ_ / 1024, 256, 0, stream>>>(y, part0, part1);
  // 8. load-balance scalar
  lb_kernel<<<1, 64, 0, stream>>>(ecnt, psum, y + SZ_);
}

// Round 7
// 616.931 us; speedup vs baseline: 1.1650x; 1.0121x over previous
//
#include <hip/hip_runtime.h>

#define B_ 4
#define N_ 1024
#define D_ 1024
#define H_ 16
#define HD_ 64
#define E_ 12
#define T_ 4096
#define FF_ 4096

static constexpr size_t SZ_ = (size_t)T_ * D_;

typedef __attribute__((ext_vector_type(8))) short bhalf8;
typedef __attribute__((ext_vector_type(4))) float f32x4;

#define GLDS(gp, lp)                                                         \
  __builtin_amdgcn_global_load_lds(                                          \
      (const __attribute__((address_space(1))) void*)(gp),                   \
      (__attribute__((address_space(3))) void*)(lp), 16, 0, 0)

__device__ __forceinline__ float wave_sum64(float v) {
#pragma unroll
  for (int o = 32; o > 0; o >>= 1) v += __shfl_down(v, o);
  return v;
}

__device__ __forceinline__ unsigned short f2bf(float f) {
  unsigned u = __float_as_uint(f);
  u += 0x7FFFu + ((u >> 16) & 1u);
  return (unsigned short)(u >> 16);
}
__device__ __forceinline__ float b2f(unsigned short s) {
  return __uint_as_float(((unsigned)s) << 16);
}
__device__ __forceinline__ unsigned addpair_bf(unsigned x, unsigned y) {
  float lo = b2f((unsigned short)(x & 0xffff)) + b2f((unsigned short)(y & 0xffff));
  float hi = b2f((unsigned short)(x >> 16)) + b2f((unsigned short)(y >> 16));
  return (unsigned)f2bf(lo) | ((unsigned)f2bf(hi) << 16);
}

__device__ __forceinline__ float gelu_f(float x) {
  float u = 0.7978845608028654f * (x + 0.044715f * x * x * x);
  u = fminf(fmaxf(u, -15.f), 15.f);
  float e = __expf(2.f * u);
  float th = (e - 1.f) / (e + 1.f);
  return 0.5f * x * (1.f + th);
}

// swizzled LDS slot for (row, kseg): keeps glds lane-contiguity AND 2-way-max
// bank aliasing on ds_read_b128 frag reads
__device__ __forceinline__ int slot_of(int row, int q) {
  return row * 4 + (q ^ ((row >> 1) & 3));
}

// ===== GEMM K-loop phase: distance-2 prefetch, triple LDS buffer, counted ===
// ===== vmcnt (never 0 mid-loop), raw barriers (no compiler vmcnt drain). ===
// Per phase p (32-wide k-step): issue GLDS for set p+2 into buf (u+2)%3;
// wait vmcnt(8) -> set p landed (vmcnt retires in order); barrier; read
// frags from buf u; 16 MFMA; end barrier (WAR vs phase p+1 overwriting the
// buffer read at p-1). All guards wave-uniform.
#define GEMM_PHASE(u, NPH_)                                                  \
  {                                                                          \
    const int p_ = kp + (u);                                                 \
    const int kpre_ = (p_ + 2) * 32;                                         \
    char* const cA_ = (char*)As[(u)];                                        \
    char* const cB_ = (char*)Bs[(u)];                                        \
    char* const pA_ = (char*)As[((u) + 2) % 3];                              \
    char* const pB_ = (char*)Bs[((u) + 2) % 3];                              \
    if (kpre_ < (NPH_)*32) {                                                 \
      GLDS(aP0 + kpre_, pA_ + s0 * 16);                                      \
      GLDS(aP1 + kpre_, pA_ + s1 * 16);                                      \
      GLDS(bP0 + kpre_, pB_ + s0 * 16);                                      \
      GLDS(bP1 + kpre_, pB_ + s1 * 16);                                      \
    }                                                                        \
    const int rem_ = (NPH_)-1 - p_;                                          \
    if (rem_ >= 2)                                                           \
      asm volatile("s_waitcnt vmcnt(8)" ::: "memory");                       \
    else if (rem_ == 1)                                                      \
      asm volatile("s_waitcnt vmcnt(4)" ::: "memory");                       \
    else                                                                     \
      asm volatile("s_waitcnt vmcnt(0)" ::: "memory");                       \
    asm volatile("s_barrier" ::: "memory");                                  \
    bhalf8 af_[4], bf_[4];                                                   \
    _Pragma("unroll") for (int t = 0; t < 4; ++t) af_[t] =                   \
        *(const bhalf8*)(cA_ + aoff[t]);                                     \
    _Pragma("unroll") for (int t = 0; t < 4; ++t) bf_[t] =                   \
        *(const bhalf8*)(cB_ + boff[t]);                                     \
    __builtin_amdgcn_s_setprio(1);                                           \
    _Pragma("unroll") for (int i = 0; i < 4; ++i)                            \
        _Pragma("unroll") for (int j = 0; j < 4; ++j) acc[i][j] =            \
        __builtin_amdgcn_mfma_f32_16x16x32_bf16(af_[i], bf_[j], acc[i][j],   \
                                                0, 0, 0);                    \
    __builtin_amdgcn_s_setprio(0);                                           \
    asm volatile("s_barrier" ::: "memory");                                  \
  }

#define GEMM_PROLOGUE()                                                      \
  GLDS(aP0, (char*)As[0] + s0 * 16);                                         \
  GLDS(aP1, (char*)As[0] + s1 * 16);                                         \
  GLDS(bP0, (char*)Bs[0] + s0 * 16);                                         \
  GLDS(bP1, (char*)Bs[0] + s1 * 16);                                         \
  GLDS(aP0 + 32, (char*)As[1] + s0 * 16);                                    \
  GLDS(aP1 + 32, (char*)As[1] + s1 * 16);                                    \
  GLDS(bP0 + 32, (char*)Bs[1] + s0 * 16);                                    \
  GLDS(bP1 + 32, (char*)Bs[1] + s1 * 16);

// ---- h = x + o0 + o1; y = h + b2 (fp32, pre-init for ffn2); hn bf16 --------
__global__ __launch_bounds__(256) void hln2_kernel(const float* __restrict__ x,
    const unsigned short* __restrict__ oa, const unsigned short* __restrict__ ob,
    const float* __restrict__ g, const float* __restrict__ be,
    const float* __restrict__ b2, float* __restrict__ y,
    unsigned short* __restrict__ hnb) {
  const int t = blockIdx.x, tid = threadIdx.x;
  const size_t base = (size_t)t * D_;
  const float4 xv = ((const float4*)(x + base))[tid];
  const ushort4 av = ((const ushort4*)(oa + base))[tid];
  const ushort4 bv = ((const ushort4*)(ob + base))[tid];
  float4 hv;
  hv.x = xv.x + b2f(av.x) + b2f(bv.x);
  hv.y = xv.y + b2f(av.y) + b2f(bv.y);
  hv.z = xv.z + b2f(av.z) + b2f(bv.z);
  hv.w = xv.w + b2f(av.w) + b2f(bv.w);
  const float4 b2v = ((const float4*)b2)[tid];
  float4 yv;
  yv.x = hv.x + b2v.x; yv.y = hv.y + b2v.y;
  yv.z = hv.z + b2v.z; yv.w = hv.w + b2v.w;
  ((float4*)(y + base))[tid] = yv;
  float s = hv.x + hv.y + hv.z + hv.w;
  float s2 = hv.x * hv.x + hv.y * hv.y + hv.z * hv.z + hv.w * hv.w;
  s = wave_sum64(s);
  s2 = wave_sum64(s2);
  __shared__ float ls[4], ls2[4];
  const int w = tid >> 6;
  if ((tid & 63) == 0) { ls[w] = s; ls2[w] = s2; }
  __syncthreads();
  const float mean = (ls[0] + ls[1] + ls[2] + ls[3]) * (1.0f / D_);
  const float var = (ls2[0] + ls2[1] + ls2[2] + ls2[3]) * (1.0f / D_) - mean * mean;
  const float inv = rsqrtf(var + 1e-5f);
  const float4 gg = ((const float4*)g)[tid];
  const float4 bb = ((const float4*)be)[tid];
  ushort4 o4;
  o4.x = f2bf((hv.x - mean) * inv * gg.x + bb.x);
  o4.y = f2bf((hv.y - mean) * inv * gg.y + bb.y);
  o4.z = f2bf((hv.z - mean) * inv * gg.z + bb.z);
  o4.w = f2bf((hv.w - mean) * inv * gg.w + bb.w);
  ((ushort4*)(hnb + base))[tid] = o4;
}

// ------- Router fused with LN1: writes bf16 xn AND routing decisions --------
__global__ __launch_bounds__(256) void router_ln(const float* __restrict__ x,
    const float* __restrict__ g, const float* __restrict__ b,
    const float* __restrict__ Wr, unsigned short* __restrict__ xnb,
    float* __restrict__ probs, int* __restrict__ topi, float2* __restrict__ topw) {
  const int t = blockIdx.x, tid = threadIdx.x;
  const float4 xv = ((const float4*)(x + (size_t)t * D_))[tid];
  float s = xv.x + xv.y + xv.z + xv.w;
  float s2 = xv.x * xv.x + xv.y * xv.y + xv.z * xv.z + xv.w * xv.w;
  s = wave_sum64(s);
  s2 = wave_sum64(s2);
  __shared__ float ls[4], ls2[4];
  const int w = tid >> 6;
  if ((tid & 63) == 0) { ls[w] = s; ls2[w] = s2; }
  __syncthreads();
  const float mean = (ls[0] + ls[1] + ls[2] + ls[3]) * (1.0f / D_);
  const float var = (ls2[0] + ls2[1] + ls2[2] + ls2[3]) * (1.0f / D_) - mean * mean;
  const float inv = rsqrtf(var + 1e-5f);
  const float4 gg = ((const float4*)g)[tid];
  const float4 bb = ((const float4*)b)[tid];
  float4 xn4;
  xn4.x = (xv.x - mean) * inv * gg.x + bb.x;
  xn4.y = (xv.y - mean) * inv * gg.y + bb.y;
  xn4.z = (xv.z - mean) * inv * gg.z + bb.z;
  xn4.w = (xv.w - mean) * inv * gg.w + bb.w;
  ushort4 u4;
  u4.x = f2bf(xn4.x); u4.y = f2bf(xn4.y);
  u4.z = f2bf(xn4.z); u4.w = f2bf(xn4.w);
  ((ushort4*)(xnb + (size_t)t * D_))[tid] = u4;
  float acc[E_];
#pragma unroll
  for (int e = 0; e < E_; ++e) {
    const float4 wv = ((const float4*)(Wr + (size_t)e * D_))[tid];
    acc[e] = xn4.x * wv.x + xn4.y * wv.y + xn4.z * wv.z + xn4.w * wv.w;
  }
#pragma unroll
  for (int e = 0; e < E_; ++e) acc[e] = wave_sum64(acc[e]);
  __shared__ float red[4][E_];
  if ((tid & 63) == 0) {
#pragma unroll
    for (int e = 0; e < E_; ++e) red[w][e] = acc[e];
  }
  __syncthreads();
  if (tid == 0) {
    float lg[E_];
    float mx = -1e30f;
#pragma unroll
    for (int e = 0; e < E_; ++e) {
      lg[e] = red[0][e] + red[1][e] + red[2][e] + red[3][e];
      mx = fmaxf(mx, lg[e]);
    }
    float p[E_];
    float sum = 0.f;
#pragma unroll
    for (int e = 0; e < E_; ++e) { p[e] = __expf(lg[e] - mx); sum += p[e]; }
    const float invs = 1.f / sum;
#pragma unroll
    for (int e = 0; e < E_; ++e) {
      p[e] *= invs;
      probs[t * E_ + e] = p[e];
    }
    int i0 = 0;
#pragma unroll
    for (int e = 1; e < E_; ++e) if (p[e] > p[i0]) i0 = e;
    int i1 = (i0 == 0) ? 1 : 0;
#pragma unroll
    for (int e = 0; e < E_; ++e) if (e != i0 && p[e] > p[i1]) i1 = e;
    const float rs = 1.f / (p[i0] + p[i1] + 1e-6f);
    topi[t] = i0 | (i1 << 8);
    topw[t] = make_float2(p[i0] * rs, p[i1] * rs);
  }
}

__global__ __launch_bounds__(256) void psum_kernel(const float* __restrict__ probs,
                                                   float* __restrict__ psum) {
  const int tid = threadIdx.x;
  float local[E_] = {};
  for (int t = tid; t < T_; t += 256) {
#pragma unroll
    for (int e = 0; e < E_; ++e) local[e] += probs[t * E_ + e];
  }
#pragma unroll
  for (int e = 0; e < E_; ++e) local[e] = wave_sum64(local[e]);
  __shared__ float red[4][E_];
  const int w = tid >> 6;
  if ((tid & 63) == 0) {
#pragma unroll
    for (int e = 0; e < E_; ++e) red[w][e] = local[e];
  }
  __syncthreads();
  if (tid < E_)
    psum[tid] = red[0][tid] + red[1][tid] + red[2][tid] + red[3][tid];
}

__global__ __launch_bounds__(256) void build_lists(const int* __restrict__ topi,
    const float2* __restrict__ topw, int* __restrict__ ecnt,
    int* __restrict__ etok, float* __restrict__ ewt) {
  const int e = blockIdx.x;
  const int tid = threadIdx.x;
  const int wid = tid >> 6, lane = tid & 63;
  __shared__ int wbase[4];
  __shared__ int base;
  if (tid == 0) base = 0;
  __syncthreads();
  for (int c = 0; c < T_; c += 256) {
    const int t = c + tid;
    const int pk = topi[t];
    const int i0 = pk & 0xFF, i1 = (pk >> 8) & 0xFF;
    const float2 w2 = topw[t];
    const int sel = (i0 == e) ? 0 : ((i1 == e) ? 1 : -1);
    const unsigned long long mask = __ballot(sel >= 0);
    const int prefix = __popcll(mask & ((1ULL << lane) - 1ULL));
    if (lane == 0) wbase[wid] = __popcll(mask);
    __syncthreads();
    if (tid == 0) {
      int s = base;
#pragma unroll
      for (int ww = 0; ww < 4; ++ww) { int cc = wbase[ww]; wbase[ww] = s; s += cc; }
      base = s;
    }
    __syncthreads();
    if (sel >= 0) {
      const int pos = wbase[wid] + prefix;
      etok[e * T_ + pos] = t | (sel << 16);
      ewt[e * T_ + pos] = sel ? w2.y : w2.x;
    }
    __syncthreads();
  }
  if (tid == 0) ecnt[e] = base;
}

// -------- fp32 -> bf16 weight conversion (float4 per thread) ----------------
__global__ __launch_bounds__(256) void cvtw_kernel(const float* __restrict__ src,
    unsigned short* __restrict__ dst) {
  const size_t i = (size_t)blockIdx.x * 256 + threadIdx.x;
  const float4 v = ((const float4*)src)[i];
  ushort4 o;
  o.x = f2bf(v.x); o.y = f2bf(v.y); o.z = f2bf(v.z); o.w = f2bf(v.w);
  ((ushort4*)dst)[i] = o;
}

// -------- 3-source weight conversion into contiguous dst regions ------------
__global__ __launch_bounds__(256) void cvtw3_kernel(const float* __restrict__ a,
    const float* __restrict__ b, const float* __restrict__ c,
    unsigned short* __restrict__ dst) {
  const int gw = (E_ * D_ * D_) / 1024;
  const int r = blockIdx.x / gw;
  const int ib = blockIdx.x - r * gw;
  const float* src = (r == 0) ? a : ((r == 1) ? b : c);
  const size_t i = (size_t)ib * 256 + threadIdx.x;
  const float4 v = ((const float4*)src)[i];
  ushort4 o;
  o.x = f2bf(v.x); o.y = f2bf(v.y); o.z = f2bf(v.z); o.w = f2bf(v.w);
  ((ushort4*)(dst + (size_t)r * E_ * D_ * D_))[i] = o;
}

// ------- MoE gathered MFMA GEMM: A bf16 (glds gather), B bf16 (glds) --------
// blockIdx.x encodes (proj, n-block): proj = bx>>3 selects weight set / output.
__global__ __launch_bounds__(256) void moe_mfma(const unsigned short* __restrict__ Ab,
    const unsigned short* __restrict__ Wb, unsigned short* __restrict__ outb,
    const int* __restrict__ ecnt, const int* __restrict__ etok,
    const float* __restrict__ ewt) {
  const int e = blockIdx.z;
  const int Me = ecnt[e];
  const int m0 = blockIdx.y * 128;
  if (m0 >= Me) return;
  const int proj = blockIdx.x >> 3;
  const int n0 = (blockIdx.x & 7) * 128;
  const unsigned short* W = Wb + ((size_t)proj * E_ + e) * D_ * D_;
  unsigned short* out = outb + (size_t)proj * 2 * SZ_;
  __shared__ __align__(16) unsigned short As[3][128 * 32];
  __shared__ __align__(16) unsigned short Bs[3][128 * 32];
  __shared__ int stok[128];
  __shared__ float swt[128];
  const int tid = threadIdx.x;
  if (tid < 128) {
    const int s = m0 + tid;
    if (s < Me) { stok[tid] = etok[e * T_ + s]; swt[tid] = ewt[e * T_ + s]; }
    else        { stok[tid] = 0;                swt[tid] = 0.f; }
  }
  __syncthreads();
  const int s0 = tid, s1 = tid + 256;
  const int r0 = s0 >> 2, q0 = (s0 & 3) ^ ((r0 >> 1) & 3);
  const int r1 = s1 >> 2, q1 = (s1 & 3) ^ ((r1 >> 1) & 3);
  const unsigned short* aP0 = Ab + (size_t)(stok[r0] & 0xFFFF) * D_ + q0 * 8;
  const unsigned short* aP1 = Ab + (size_t)(stok[r1] & 0xFFFF) * D_ + q1 * 8;
  const unsigned short* bP0 = W + (size_t)(n0 + r0) * D_ + q0 * 8;
  const unsigned short* bP1 = W + (size_t)(n0 + r1) * D_ + q1 * 8;
  const int wave = tid >> 6, lane = tid & 63;
  const int wm0 = (wave >> 1) * 64, wn0 = (wave & 1) * 64;
  const int lr = lane & 15, lq = lane >> 4;
  int aoff[4], boff[4];
#pragma unroll
  for (int t = 0; t < 4; ++t) {
    aoff[t] = slot_of(wm0 + t * 16 + lr, lq) * 16;
    boff[t] = slot_of(wn0 + t * 16 + lr, lq) * 16;
  }
  f32x4 acc[4][4];
#pragma unroll
  for (int i = 0; i < 4; ++i)
#pragma unroll
    for (int j = 0; j < 4; ++j) acc[i][j] = (f32x4){0.f, 0.f, 0.f, 0.f};
  GEMM_PROLOGUE()
  for (int kp = 0; kp < 32; kp += 3) {
    GEMM_PHASE(0, 32)
    if (kp + 1 < 32) GEMM_PHASE(1, 32)
    if (kp + 2 < 32) GEMM_PHASE(2, 32)
  }
#pragma unroll
  for (int mt = 0; mt < 4; ++mt)
#pragma unroll
    for (int nt = 0; nt < 4; ++nt) {
      const f32x4 c = acc[mt][nt];
      const int col = n0 + wn0 + nt * 16 + lr;
#pragma unroll
      for (int r = 0; r < 4; ++r) {
        const int row = wm0 + mt * 16 + lq * 4 + r;
        if (m0 + row < Me) {
          const int pk = stok[row];
          out[(size_t)(pk >> 16) * SZ_ + (size_t)(pk & 0xFFFF) * D_ + col] =
              f2bf(c[r] * swt[row]);
        }
      }
    }
}

// ------- FFN1 MFMA: midb = bf16(gelu(hnb @ W1b.T + b1)) ---------------------
__global__ __launch_bounds__(256) void ffn1_mfma(const unsigned short* __restrict__ Ab,
    const unsigned short* __restrict__ Bb, const float* __restrict__ bias,
    unsigned short* __restrict__ mid) {
  const int m0 = blockIdx.y * 128, n0 = blockIdx.x * 128;
  __shared__ __align__(16) unsigned short As[3][128 * 32];
  __shared__ __align__(16) unsigned short Bs[3][128 * 32];
  const int tid = threadIdx.x;
  const int s0 = tid, s1 = tid + 256;
  const int r0 = s0 >> 2, q0 = (s0 & 3) ^ ((r0 >> 1) & 3);
  const int r1 = s1 >> 2, q1 = (s1 & 3) ^ ((r1 >> 1) & 3);
  const unsigned short* aP0 = Ab + (size_t)(m0 + r0) * D_ + q0 * 8;
  const unsigned short* aP1 = Ab + (size_t)(m0 + r1) * D_ + q1 * 8;
  const unsigned short* bP0 = Bb + (size_t)(n0 + r0) * D_ + q0 * 8;
  const unsigned short* bP1 = Bb + (size_t)(n0 + r1) * D_ + q1 * 8;
  const int wave = tid >> 6, lane = tid & 63;
  const int wm0 = (wave >> 1) * 64, wn0 = (wave & 1) * 64;
  const int lr = lane & 15, lq = lane >> 4;
  int aoff[4], boff[4];
#pragma unroll
  for (int t = 0; t < 4; ++t) {
    aoff[t] = slot_of(wm0 + t * 16 + lr, lq) * 16;
    boff[t] = slot_of(wn0 + t * 16 + lr, lq) * 16;
  }
  f32x4 acc[4][4];
#pragma unroll
  for (int i = 0; i < 4; ++i)
#pragma unroll
    for (int j = 0; j < 4; ++j) acc[i][j] = (f32x4){0.f, 0.f, 0.f, 0.f};
  GEMM_PROLOGUE()
  for (int kp = 0; kp < 32; kp += 3) {
    GEMM_PHASE(0, 32)
    if (kp + 1 < 32) GEMM_PHASE(1, 32)
    if (kp + 2 < 32) GEMM_PHASE(2, 32)
  }
  float bcol[4];
#pragma unroll
  for (int nt = 0; nt < 4; ++nt) bcol[nt] = bias[n0 + wn0 + nt * 16 + lr];
#pragma unroll
  for (int mt = 0; mt < 4; ++mt)
#pragma unroll
    for (int nt = 0; nt < 4; ++nt) {
      const f32x4 c = acc[mt][nt];
      const int col = n0 + wn0 + nt * 16 + lr;
#pragma unroll
      for (int r = 0; r < 4; ++r) {
        const int row = m0 + wm0 + mt * 16 + lq * 4 + r;
        mid[(size_t)row * FF_ + col] = f2bf(gelu_f(c[r] + bcol[nt]));
      }
    }
}

// ------- FFN2 split-K=2 MFMA: part[z] = midb[:, zK:(z+1)K] @ W2b[...].T -----
__global__ __launch_bounds__(256) void ffn2_split(const unsigned short* __restrict__ Ab,
    const unsigned short* __restrict__ Bb, float* __restrict__ part0,
    float* __restrict__ part1) {
  const int m0 = blockIdx.y * 128, n0 = blockIdx.x * 128;
  const int k0 = blockIdx.z * (FF_ / 2);
  float* const part = blockIdx.z ? part1 : part0;
  __shared__ __align__(16) unsigned short As[3][128 * 32];
  __shared__ __align__(16) unsigned short Bs[3][128 * 32];
  const int tid = threadIdx.x;
  const int s0 = tid, s1 = tid + 256;
  const int r0 = s0 >> 2, q0 = (s0 & 3) ^ ((r0 >> 1) & 3);
  const int r1 = s1 >> 2, q1 = (s1 & 3) ^ ((r1 >> 1) & 3);
  const unsigned short* aP0 = Ab + (size_t)(m0 + r0) * FF_ + q0 * 8 + k0;
  const unsigned short* aP1 = Ab + (size_t)(m0 + r1) * FF_ + q1 * 8 + k0;
  const unsigned short* bP0 = Bb + (size_t)(n0 + r0) * FF_ + q0 * 8 + k0;
  const unsigned short* bP1 = Bb + (size_t)(n0 + r1) * FF_ + q1 * 8 + k0;
  const int wave = tid >> 6, lane = tid & 63;
  const int wm0 = (wave >> 1) * 64, wn0 = (wave & 1) * 64;
  const int lr = lane & 15, lq = lane >> 4;
  int aoff[4], boff[4];
#pragma unroll
  for (int t = 0; t < 4; ++t) {
    aoff[t] = slot_of(wm0 + t * 16 + lr, lq) * 16;
    boff[t] = slot_of(wn0 + t * 16 + lr, lq) * 16;
  }
  f32x4 acc[4][4];
#pragma unroll
  for (int i = 0; i < 4; ++i)
#pragma unroll
    for (int j = 0; j < 4; ++j) acc[i][j] = (f32x4){0.f, 0.f, 0.f, 0.f};
  GEMM_PROLOGUE()
  for (int kp = 0; kp < 64; kp += 3) {
    GEMM_PHASE(0, 64)
    if (kp + 1 < 64) GEMM_PHASE(1, 64)
    if (kp + 2 < 64) GEMM_PHASE(2, 64)
  }
#pragma unroll
  for (int mt = 0; mt < 4; ++mt)
#pragma unroll
    for (int nt = 0; nt < 4; ++nt) {
      const f32x4 c = acc[mt][nt];
      const int col = n0 + wn0 + nt * 16 + lr;
#pragma unroll
      for (int r = 0; r < 4; ++r) {
        const int row = m0 + wm0 + mt * 16 + lq * 4 + r;
        part[(size_t)row * D_ + col] = c[r];
      }
    }
}

// ---------------- y += p0 + p1 (float4 per thread) --------------------------
__global__ __launch_bounds__(256) void add3_kernel(float* __restrict__ y,
    const float* __restrict__ p0, const float* __restrict__ p1) {
  const size_t i = (size_t)blockIdx.x * 256 + threadIdx.x;
  const float4 a = ((const float4*)y)[i];
  const float4 u = ((const float4*)p0)[i];
  const float4 v = ((const float4*)p1)[i];
  float4 o;
  o.x = a.x + u.x + v.x;
  o.y = a.y + u.y + v.y;
  o.z = a.z + u.z + v.z;
  o.w = a.w + u.w + v.w;
  ((float4*)y)[i] = o;
}

// ------- bf16 in-place slot0 += slot1 for 3 regions spaced 2*SZ -------------
__global__ __launch_bounds__(256) void add2b3_kernel(unsigned short* __restrict__ base) {
  const int reg = blockIdx.x >> 11;             // 2048 blocks per region
  const int ib = blockIdx.x & 2047;
  unsigned short* a = base + (size_t)reg * 2 * SZ_;
  const unsigned short* b = a + SZ_;
  const size_t i = (size_t)ib * 256 + threadIdx.x;
  uint4 av = ((uint4*)a)[i];
  const uint4 bv = ((const uint4*)b)[i];
  av.x = addpair_bf(av.x, bv.x);
  av.y = addpair_bf(av.y, bv.y);
  av.z = addpair_bf(av.z, bv.z);
  av.w = addpair_bf(av.w, bv.w);
  ((uint4*)a)[i] = av;
}

// ---------------- Flash attention (MFMA bf16, fp32 softmax) -----------------
__global__ __launch_bounds__(256) void attn_kernel(const unsigned short* __restrict__ q,
    const unsigned short* __restrict__ k, const unsigned short* __restrict__ v,
    unsigned short* __restrict__ out) {
  const int bh = blockIdx.x;
  const int b = bh >> 4, h = bh & 15;
  const int q0 = blockIdx.y * 64;
  const int tid = threadIdx.x;
  const int wave = tid >> 6, lane = tid & 63;
  const int lc = lane & 15, lg = lane >> 4;

  __shared__ __align__(16) unsigned short Ks[64 * 64];   // [kv][d] swizzled
  __shared__ __align__(16) unsigned short Vt[64 * 64];   // [d][kv] swizzled
  __shared__ __align__(16) unsigned short Pl[4][16 * 64]; // per-wave [q][kv] swizzled
  char* const KsC = (char*)Ks;
  char* const VtC = (char*)Vt;
  char* const PlC = (char*)&Pl[wave][0];

  bhalf8 qf0, qf1;
  {
    const unsigned short* qp =
        q + ((size_t)(b * N_ + q0 + wave * 16 + lc)) * D_ + h * HD_ + lg * 8;
    qf0 = *(const bhalf8*)qp;
    qf1 = *(const bhalf8*)(qp + 32);
  }

  int off[4][2];
#pragma unroll
  for (int t = 0; t < 4; ++t)
#pragma unroll
    for (int ch = 0; ch < 2; ++ch)
      off[t][ch] = (t * 16 + lc) * 128 + (((ch * 4 + lg) ^ (lc & 7)) << 4);

  const int krow = tid >> 2, ks0 = tid & 3;
  const unsigned short* const kgp =
      k + ((size_t)(b * N_ + krow)) * D_ + h * HD_ + ks0 * 8;
  const int kwo0 = krow * 128 + ((ks0 ^ (krow & 7)) << 4);
  const int kwo1 = krow * 128 + (((ks0 ^ 4) ^ (krow & 7)) << 4);
  const int vkv = (tid & 31) * 2, vd0 = (tid >> 5) * 8;
  const unsigned short* const vgp =
      v + ((size_t)(b * N_ + vkv)) * D_ + h * HD_ + vd0;
  int vwo[8];
#pragma unroll
  for (int c = 0; c < 8; ++c) {
    const int d = vd0 + c;
    vwo[c] = d * 128 + ((((vkv >> 3) ^ (d & 7)) << 4)) + (vkv & 7) * 2;
  }

  float m_i[4], l_i[4];
  f32x4 o_acc[4];
#pragma unroll
  for (int r = 0; r < 4; ++r) { m_i[r] = -3.0e38f; l_i[r] = 0.f; }
#pragma unroll
  for (int t = 0; t < 4; ++t) o_acc[t] = (f32x4){0.f, 0.f, 0.f, 0.f};

  uint4 ka = *(const uint4*)(kgp);
  uint4 kb = *(const uint4*)(kgp + 32);
  uint4 va = *(const uint4*)(vgp);
  uint4 vb = *(const uint4*)(vgp + D_);

  for (int kt = 0; kt < 16; ++kt) {
    __syncthreads();
    *(uint4*)(KsC + kwo0) = ka;
    *(uint4*)(KsC + kwo1) = kb;
    {
      const unsigned av4[4] = {va.x, va.y, va.z, va.w};
      const unsigned bv4[4] = {vb.x, vb.y, vb.z, vb.w};
#pragma unroll
      for (int c = 0; c < 4; ++c) {
        const unsigned w0 = (av4[c] & 0xffffu) | (bv4[c] << 16);
        const unsigned w1 = (av4[c] >> 16) | (bv4[c] & 0xffff0000u);
        *(unsigned*)(VtC + vwo[2 * c]) = w0;
        *(unsigned*)(VtC + vwo[2 * c + 1]) = w1;
      }
    }
    __syncthreads();
    if (kt < 15) {
      const size_t go = (size_t)(kt + 1) * 64 * D_;
      ka = *(const uint4*)(kgp + go);
      kb = *(const uint4*)(kgp + go + 32);
      va = *(const uint4*)(vgp + go);
      vb = *(const uint4*)(vgp + go + D_);
    }
    f32x4 s4[4];
#pragma unroll
    for (int t = 0; t < 4; ++t) {
      f32x4 acc = (f32x4){0.f, 0.f, 0.f, 0.f};
      acc = __builtin_amdgcn_mfma_f32_16x16x32_bf16(
          qf0, *(const bhalf8*)(KsC + off[t][0]), acc, 0, 0, 0);
      acc = __builtin_amdgcn_mfma_f32_16x16x32_bf16(
          qf1, *(const bhalf8*)(KsC + off[t][1]), acc, 0, 0, 0);
      s4[t] = acc;
    }
    float alpha[4];
#pragma unroll
    for (int r = 0; r < 4; ++r) {
      const float e0 = s4[0][r] * 0.125f, e1 = s4[1][r] * 0.125f;
      const float e2 = s4[2][r] * 0.125f, e3 = s4[3][r] * 0.125f;
      float mt = fmaxf(fmaxf(e0, e1), fmaxf(e2, e3));
#pragma unroll
      for (int o = 8; o > 0; o >>= 1) mt = fmaxf(mt, __shfl_xor(mt, o));
      const float mn = fmaxf(m_i[r], mt);
      alpha[r] = __expf(m_i[r] - mn);
      m_i[r] = mn;
      const float p0 = __expf(e0 - mn), p1 = __expf(e1 - mn);
      const float p2 = __expf(e2 - mn), p3 = __expf(e3 - mn);
      float rs = p0 + p1 + p2 + p3;
#pragma unroll
      for (int o = 8; o > 0; o >>= 1) rs += __shfl_xor(rs, o);
      l_i[r] = l_i[r] * alpha[r] + rs;
      const int qrow = 4 * lg + r;
      const int rb = qrow * 128 + (lc & 7) * 2;
      const int sw = qrow & 7;
      *(unsigned short*)(PlC + rb + (((0 + (lc >> 3)) ^ sw) << 4)) = f2bf(p0);
      *(unsigned short*)(PlC + rb + (((2 + (lc >> 3)) ^ sw) << 4)) = f2bf(p1);
      *(unsigned short*)(PlC + rb + (((4 + (lc >> 3)) ^ sw) << 4)) = f2bf(p2);
      *(unsigned short*)(PlC + rb + (((6 + (lc >> 3)) ^ sw) << 4)) = f2bf(p3);
    }
#pragma unroll
    for (int t = 0; t < 4; ++t) {
      f32x4 o = o_acc[t];
      o[0] *= alpha[0]; o[1] *= alpha[1]; o[2] *= alpha[2]; o[3] *= alpha[3];
      o_acc[t] = o;
    }
    const bhalf8 pf0 = *(const bhalf8*)(PlC + off[0][0]);
    const bhalf8 pf1 = *(const bhalf8*)(PlC + off[0][1]);
#pragma unroll
    for (int t = 0; t < 4; ++t) {
      o_acc[t] = __builtin_amdgcn_mfma_f32_16x16x32_bf16(
          pf0, *(const bhalf8*)(VtC + off[t][0]), o_acc[t], 0, 0, 0);
      o_acc[t] = __builtin_amdgcn_mfma_f32_16x16x32_bf16(
          pf1, *(const bhalf8*)(VtC + off[t][1]), o_acc[t], 0, 0, 0);
    }
  }
  const size_t obase = ((size_t)(b * N_ + q0 + wave * 16)) * D_ + h * HD_;
#pragma unroll
  for (int r = 0; r < 4; ++r) {
    const float inv = 1.f / l_i[r];
    const size_t rbase = obase + (size_t)(4 * lg + r) * D_;
#pragma unroll
    for (int t = 0; t < 4; ++t)
      out[rbase + t * 16 + lc] = f2bf(o_acc[t][r] * inv);
  }
}

// ---------------- load-balance scalar ---------------------------------------
__global__ void lb_kernel(const int* __restrict__ ecnt,
                          const float* __restrict__ psum, float* __restrict__ out) {
  if (threadIdx.x == 0 && blockIdx.x == 0) {
    float tot = 0.f;
    for (int e = 0; e < E_; ++e) tot += (float)ecnt[e];
    float s = 0.f;
    for (int e = 0; e < E_; ++e) s += (float)ecnt[e] / (tot + 1e-6f) * psum[e];
    out[0] = s * (float)E_;
  }
}

extern "C" void kernel_launch(void* const* d_in, const int* in_sizes, int n_in,
                              void* d_out, int out_size, void* d_ws, size_t ws_size,
                              hipStream_t stream) {
  (void)in_sizes; (void)n_in; (void)out_size;
  const float* x  = (const float*)d_in[0];
  const float* Wr = (const float*)d_in[1];
  const float* Wq = (const float*)d_in[2];
  const float* Wk = (const float*)d_in[3];
  const float* Wv = (const float*)d_in[4];
  const float* Wo = (const float*)d_in[5];
  const float* W1 = (const float*)d_in[6];
  const float* b1 = (const float*)d_in[7];
  const float* W2 = (const float*)d_in[8];
  const float* b2 = (const float*)d_in[9];
  const float* g1 = (const float*)d_in[10];
  const float* be1 = (const float*)d_in[11];
  const float* g2 = (const float*)d_in[12];
  const float* be2 = (const float*)d_in[13];
  float* y = (float*)d_out;

  // ---- workspace layout --------------------------------------------------
  // big path (>=136MB): Rb3 [0,72MB) holds Wq|Wk|Wv bf16 for ONE fused qkv
  //   moe dispatch; after it, Wo->[0,24), W1b->[24,32), W2b->[32,40),
  //   midb->[40,72) overlay the dead regions.
  // small path: 96.6MB layout (per-weight serial cvtw+moe).
  const bool big = ws_size >= (size_t)136 * 1024 * 1024;
  char* p = (char*)d_ws;
  unsigned short *Rb, *xnb, *q2b, *WoB, *W1b, *W2b, *midb;
  char* tail;
  if (big) {
    Rb  = (unsigned short*)p;                              // 72 MB (3 expert sets)
    xnb = (unsigned short*)(p + 75497472);                 // 8 MB
    q2b = (unsigned short*)(p + 75497472 + 8388608);       // 48 MB (q|k|v, 2 slots each)
    tail = p + 75497472 + 8388608 + 6 * SZ_ * 2;
    WoB  = Rb;                                             // after fused moe
    W1b  = (unsigned short*)(p + 25165824);
    W2b  = (unsigned short*)(p + 33554432);
    midb = (unsigned short*)(p + 41943040);                // 32 MB
  } else {
    Rb  = (unsigned short*)p;                              // 24 MB (1 expert set)
    xnb = (unsigned short*)(p + 25165824);
    q2b = xnb + SZ_;
    W1b = q2b + 6 * SZ_;
    W2b = W1b + (size_t)FF_ * D_;
    tail = (char*)(W2b + (size_t)FF_ * D_);
    WoB  = Rb;
    midb = (unsigned short*)d_ws;                          // 32 MB over Rb+xnb
  }
  unsigned short* k2b = q2b + 2 * SZ_;
  unsigned short* v2b = k2b + 2 * SZ_;
  float* psum = (float*)tail;            tail += E_ * 4;
  int* ecnt = (int*)tail;                tail += E_ * 4;
  int* etok = (int*)tail;                tail += (size_t)E_ * T_ * 4;
  float* ewt = (float*)tail;             tail += (size_t)E_ * T_ * 4;
  float* probs = (float*)tail;           tail += (size_t)T_ * E_ * 4;
  int* topi = (int*)tail;                tail += T_ * 4;
  float2* topw = (float2*)tail;
  // overlays (dead at time of reuse):
  unsigned short* attb = v2b + SZ_;      // attn out (v slot1 dead after add2b3)
  unsigned short* o2b  = q2b;            // o-proj 2 slots (q dead post-attn)
  unsigned short* hnb  = v2b;            // hn bf16 (v slot0 dead post-attn)
  float* part0         = (float*)k2b;    // ffn2 partial z=0 (k dead post-attn)
  float* part1         = (float*)v2b;    // ffn2 partial z=1 (v dead post-ffn1)

  const int gw = (E_ * D_ * D_) / 1024;
  // 1. Router (fused LN1: writes bf16 xnb + routing) + lists
  router_ln<<<T_, 256, 0, stream>>>(x, g1, be1, Wr, xnb, probs, topi, topw);
  psum_kernel<<<1, 256, 0, stream>>>(probs, psum);
  build_lists<<<E_, 256, 0, stream>>>(topi, topw, ecnt, etok, ewt);
  // 2. MoE q,k,v projections
  if (big) {
    cvtw3_kernel<<<3 * gw, 256, 0, stream>>>(Wq, Wk, Wv, Rb);
    moe_mfma<<<dim3(24, T_ / 128, E_), 256, 0, stream>>>(xnb, Rb, q2b, ecnt, etok, ewt);
    cvtw_kernel<<<gw, 256, 0, stream>>>(Wo, WoB);
    cvtw_kernel<<<(FF_ * D_) / 1024, 256, 0, stream>>>(W1, W1b);
    cvtw_kernel<<<(FF_ * D_) / 1024, 256, 0, stream>>>(W2, W2b);
  } else {
    cvtw_kernel<<<(FF_ * D_) / 1024, 256, 0, stream>>>(W1, W1b);
    cvtw_kernel<<<(FF_ * D_) / 1024, 256, 0, stream>>>(W2, W2b);
    cvtw_kernel<<<gw, 256, 0, stream>>>(Wq, Rb);
    moe_mfma<<<dim3(8, T_ / 128, E_), 256, 0, stream>>>(xnb, Rb, q2b, ecnt, etok, ewt);
    cvtw_kernel<<<gw, 256, 0, stream>>>(Wk, Rb);
    moe_mfma<<<dim3(8, T_ / 128, E_), 256, 0, stream>>>(xnb, Rb, k2b, ecnt, etok, ewt);
    cvtw_kernel<<<gw, 256, 0, stream>>>(Wv, Rb);
    moe_mfma<<<dim3(8, T_ / 128, E_), 256, 0, stream>>>(xnb, Rb, v2b, ecnt, etok, ewt);
    cvtw_kernel<<<gw, 256, 0, stream>>>(Wo, Rb);
  }
  // 3. Combine expert slots (bf16, one dispatch over q/k/v regions)
  add2b3_kernel<<<3 * (SZ_ / 2048), 256, 0, stream>>>(q2b);
  // 4. Attention (MFMA flash; out -> v2b slot1)
  attn_kernel<<<dim3(B_ * H_, N_ / 64), 256, 0, stream>>>(q2b, k2b, v2b, attb);
  // 5. Output projection (2 slots into o2b = q2b)
  moe_mfma<<<dim3(8, T_ / 128, E_), 256, 0, stream>>>(attb, WoB, o2b, ecnt, etok, ewt);
  // 6. h = x + o0 + o1 ; y = h + b2 (ffn2 pre-init) ; hn = LN2(h)
  hln2_kernel<<<T_, 256, 0, stream>>>(x, o2b, o2b + SZ_, g2, be2, b2, y, hnb);
  // 7. FFN (MFMA; ffn2 split-K=2 into fp32 partials, then combine)
  ffn1_mfma<<<dim3(FF_ / 128, T_ / 128), 256, 0, stream>>>(hnb, W1b, b1, midb);
  ffn2_split<<<dim3(D_ / 128, T_ / 128, 2), 256, 0, stream>>>(midb, W2b, part0, part1);
  add3_kernel<<<SZ_ / 1024, 256, 0, stream>>>(y, part0, part1);
  // 8. load-balance scalar
  lb_kernel<<<1, 64, 0, stream>>>(ecnt, psum, y + SZ_);
}